// Round 2
// baseline (153.524 us; speedup 1.0000x reference)
//
#include <hip/hip_runtime.h>

#define NB 2
#define SEQ 2048
#define NH 8
#define HD 64
#define DMODEL 512
#define WSPAN 64
#define MROWS (NB * SEQ) /* 4096 */

typedef __attribute__((ext_vector_type(4))) float f32x4;
typedef __attribute__((ext_vector_type(4))) int i32x4;

static __device__ __forceinline__ float bf2f(unsigned short u) {
    return __uint_as_float(((unsigned int)u) << 16);
}
static __device__ __forceinline__ unsigned short f2bf(float f) {
    unsigned int x = __float_as_uint(f);
    x += 0x7fffu + ((x >> 16) & 1u);   // RNE
    return (unsigned short)(x >> 16);
}

// ---------------------------------------------------------------- cvt f32->bf16
struct CvtArgs {
    const float* src[7];
    unsigned short* dst[7];
    int n8[7];
};

__global__ __launch_bounds__(256) void cvt_all(CvtArgs a) {
    const int ai = blockIdx.y;
    const int idx = blockIdx.x * 256 + threadIdx.x;
    if (idx >= a.n8[ai]) return;
    const float* s = a.src[ai] + (size_t)idx * 8;
    float4 f0 = *(const float4*)s;
    float4 f1 = *(const float4*)(s + 4);
    i32x4 o;
    o[0] = (int)((unsigned)f2bf(f0.x) | ((unsigned)f2bf(f0.y) << 16));
    o[1] = (int)((unsigned)f2bf(f0.z) | ((unsigned)f2bf(f0.w) << 16));
    o[2] = (int)((unsigned)f2bf(f1.x) | ((unsigned)f2bf(f1.y) << 16));
    o[3] = (int)((unsigned)f2bf(f1.z) | ((unsigned)f2bf(f1.w) << 16));
    *(i32x4*)(a.dst[ai] + (size_t)idx * 8) = o;
}

// ---------------------------------------------------------------- GEMM (bf16 in, MFMA)
#define GBM 64
#define GBN 128
#define GBK 32
#define GPAD 40   // LDS row stride (bf16 elems): 80B rows -> ~2-way banked b128 reads

static __device__ __forceinline__ f32x4 mfma16(i32x4 a, i32x4 b, f32x4 c) {
    asm("v_mfma_f32_16x16x32_bf16 %0, %1, %2, %0" : "+v"(c) : "v"(a), "v"(b));
    return c;
}

template <bool OUT_F32>
static __device__ __forceinline__ void gemm_core(const unsigned short* __restrict__ A,
                                                 const unsigned short* __restrict__ W,
                                                 void* __restrict__ C, int m0, int n0) {
    constexpr int N = DMODEL, K = DMODEL;
    __shared__ __align__(16) unsigned short a_lds[GBM][GPAD];
    __shared__ __align__(16) unsigned short w_lds[GBN][GPAD];
    const int t = threadIdx.x;
    const int lane = t & 63;
    const int wv = t >> 6;
    // staging coords
    const int sa_m = t >> 2;          // 0..63
    const int sa_k = (t & 3) * 8;     // 0,8,16,24
    const int sw_n = t & 127;         // 0..127
    const int sw_k = (t >> 7) * 16;   // 0 or 16
    // fragment coords (verified layout: row/col = lane&15, k = (lane>>4)*8)
    const int fr = lane & 15;
    const int fk = (lane >> 4) * 8;
    const int wm = (wv & 1) * 32;
    const int wn = (wv >> 1) * 64;

    f32x4 acc[2][4];
#pragma unroll
    for (int i = 0; i < 2; ++i)
#pragma unroll
        for (int j = 0; j < 4; ++j) acc[i][j] = (f32x4){0.f, 0.f, 0.f, 0.f};

    for (int k0 = 0; k0 < K; k0 += GBK) {
        // A chunk: 8 contiguous bf16 per thread
        i32x4 av = *(const i32x4*)(A + (size_t)(m0 + sa_m) * K + k0 + sa_k);
        // W chunk: 16 k-strided bf16 per thread (transposed into LDS as W^T)
        const unsigned short* wp = W + (size_t)(k0 + sw_k) * N + n0 + sw_n;
        unsigned int ww[8];
#pragma unroll
        for (int j2 = 0; j2 < 8; ++j2) {
            unsigned int lo = wp[(size_t)(2 * j2) * N];
            unsigned int hi = wp[(size_t)(2 * j2 + 1) * N];
            ww[j2] = (lo & 0xffffu) | (hi << 16);
        }
        i32x4 w0 = {(int)ww[0], (int)ww[1], (int)ww[2], (int)ww[3]};
        i32x4 w1 = {(int)ww[4], (int)ww[5], (int)ww[6], (int)ww[7]};
        __syncthreads();
        *(i32x4*)&a_lds[sa_m][sa_k] = av;
        *(i32x4*)&w_lds[sw_n][sw_k] = w0;
        *(i32x4*)&w_lds[sw_n][sw_k + 8] = w1;
        __syncthreads();
        i32x4 af0 = *(const i32x4*)&a_lds[wm + fr][fk];
        i32x4 af1 = *(const i32x4*)&a_lds[wm + 16 + fr][fk];
#pragma unroll
        for (int ni = 0; ni < 4; ++ni) {
            i32x4 bfr = *(const i32x4*)&w_lds[wn + ni * 16 + fr][fk];
            acc[0][ni] = mfma16(af0, bfr, acc[0][ni]);
            acc[1][ni] = mfma16(af1, bfr, acc[1][ni]);
        }
    }
    asm volatile("s_nop 7\n\ts_nop 7\n\ts_nop 7" ::);  // MFMA->VALU read hazard
#pragma unroll
    for (int mi = 0; mi < 2; ++mi) {
#pragma unroll
        for (int ni = 0; ni < 4; ++ni) {
#pragma unroll
            for (int r = 0; r < 4; ++r) {
                const int row = m0 + wm + mi * 16 + (lane >> 4) * 4 + r;
                const int col = n0 + wn + ni * 16 + fr;
                if constexpr (OUT_F32)
                    ((float*)C)[(size_t)row * N + col] = acc[mi][ni][r];
                else
                    ((unsigned short*)C)[(size_t)row * N + col] = f2bf(acc[mi][ni][r]);
            }
        }
    }
}

__global__ __launch_bounds__(256) void gemm_proj(
    const unsigned short* __restrict__ qx, const unsigned short* __restrict__ kx,
    const unsigned short* __restrict__ vx, const unsigned short* __restrict__ wqx,
    const unsigned short* __restrict__ wkx, const unsigned short* __restrict__ wvx,
    unsigned short* __restrict__ Qp, unsigned short* __restrict__ Kp,
    unsigned short* __restrict__ Vp) {
    const unsigned short* A;
    const unsigned short* W;
    unsigned short* C;
    if (blockIdx.z == 0) { A = qx; W = wqx; C = Qp; }
    else if (blockIdx.z == 1) { A = kx; W = wkx; C = Kp; }
    else { A = vx; W = wvx; C = Vp; }
    gemm_core<false>(A, W, C, blockIdx.x * GBM, blockIdx.y * GBN);
}

__global__ __launch_bounds__(256) void gemm_out(const unsigned short* __restrict__ Op,
                                                const unsigned short* __restrict__ wox,
                                                float* __restrict__ out) {
    gemm_core<true>(Op, wox, out, blockIdx.x * GBM, blockIdx.y * GBN);
}

// ---------------------------------------------------------------- windowed attention
// grid: (SEQ/64, NH, NB); 256 threads = 4 waves; wave handles 16 queries.
// lane = key-offset for scores (bf16 K^T column reads, conflict-free),
// lane = dim for PV (row-broadcast V reads), p broadcast via v_readlane.
__global__ __launch_bounds__(256) void attn_win(const unsigned short* __restrict__ Qp,
                                                const unsigned short* __restrict__ Kp,
                                                const unsigned short* __restrict__ Vp,
                                                unsigned short* __restrict__ Op) {
    __shared__ unsigned short ktT[HD][130];            // [d][l] bf16, pad->conflict-free
    __shared__ __align__(16) float vt[128][68];        // [l][d] f32, pad 68
    __shared__ __align__(16) unsigned short qt[64][64];// [i][d] bf16
    const int tile = blockIdx.x, h = blockIdx.y, b = blockIdx.z;
    const int t0 = tile * 64;
    const int tid = threadIdx.x, lane = tid & 63, wv = tid >> 6;
    const int hcol = h * HD;
    const size_t base = (size_t)b * SEQ * DMODEL;

    {   // stage K window (bf16, transposed) and V window (f32)
        const int l = tid >> 1;
        const int dg = (tid & 1) * 32;
        int j = t0 - (WSPAN - 1) + l;
        int jc = j < 0 ? 0 : (j > SEQ - 1 ? SEQ - 1 : j);
        const unsigned short* kp = Kp + base + (size_t)jc * DMODEL + hcol + dg;
        const unsigned short* vp = Vp + base + (size_t)jc * DMODEL + hcol + dg;
#pragma unroll
        for (int u = 0; u < 32; u += 8) {
            i32x4 kv = *(const i32x4*)(kp + u);
            i32x4 vv = *(const i32x4*)(vp + u);
#pragma unroll
            for (int e2 = 0; e2 < 4; ++e2) {
                unsigned int wk = (unsigned int)kv[e2];
                ktT[dg + u + 2 * e2][l] = (unsigned short)(wk & 0xffffu);
                ktT[dg + u + 2 * e2 + 1][l] = (unsigned short)(wk >> 16);
            }
            f32x4 va = {bf2f((unsigned short)((unsigned)vv[0] & 0xffffu)),
                        bf2f((unsigned short)((unsigned)vv[0] >> 16)),
                        bf2f((unsigned short)((unsigned)vv[1] & 0xffffu)),
                        bf2f((unsigned short)((unsigned)vv[1] >> 16))};
            f32x4 vb = {bf2f((unsigned short)((unsigned)vv[2] & 0xffffu)),
                        bf2f((unsigned short)((unsigned)vv[2] >> 16)),
                        bf2f((unsigned short)((unsigned)vv[3] & 0xffffu)),
                        bf2f((unsigned short)((unsigned)vv[3] >> 16))};
            *(f32x4*)&vt[l][dg + u] = va;
            *(f32x4*)&vt[l][dg + u + 4] = vb;
        }
    }
    {   // stage Q tile (bf16 copy)
        const int i = tid >> 2;
        const int cg = (tid & 3) * 16;
        const unsigned short* qp = Qp + base + (size_t)(t0 + i) * DMODEL + hcol + cg;
        *(i32x4*)&qt[i][cg] = *(const i32x4*)qp;
        *(i32x4*)&qt[i][cg + 8] = *(const i32x4*)(qp + 8);
    }
    __syncthreads();

    for (int qi = 0; qi < 16; ++qi) {
        const int i = wv * 16 + qi;
        const int li = i + lane;  // local key row for this lane, <=126
        float s0 = 0.f, s1 = 0.f, s2 = 0.f, s3 = 0.f;
#pragma unroll
        for (int d0 = 0; d0 < HD; d0 += 4) {
            unsigned long long qw = *(const unsigned long long*)&qt[i][d0];  // broadcast
            s0 += bf2f((unsigned short)qw) * bf2f(ktT[d0 + 0][li]);
            s1 += bf2f((unsigned short)(qw >> 16)) * bf2f(ktT[d0 + 1][li]);
            s2 += bf2f((unsigned short)(qw >> 32)) * bf2f(ktT[d0 + 2][li]);
            s3 += bf2f((unsigned short)(qw >> 48)) * bf2f(ktT[d0 + 3][li]);
        }
        float sc = (s0 + s1) + (s2 + s3);
        const int tg = t0 + i;
        float sv = sc * 0.125f;  // 1/sqrt(64)
        if (tg - (WSPAN - 1) + lane < 0) sv = -__builtin_inff();  // causal-window mask
        float mx = sv;
#pragma unroll
        for (int off = 32; off > 0; off >>= 1) mx = fmaxf(mx, __shfl_xor(mx, off));
        float p = __expf(sv - mx);
        float sum = p;
#pragma unroll
        for (int off = 32; off > 0; off >>= 1) sum += __shfl_xor(sum, off);
        p = p / sum;
        float o0 = 0.f, o1 = 0.f, o2 = 0.f, o3 = 0.f;
#pragma unroll
        for (int s = 0; s < WSPAN; s += 4) {
            float p0 = __int_as_float(__builtin_amdgcn_readlane(__float_as_int(p), s));
            float p1 = __int_as_float(__builtin_amdgcn_readlane(__float_as_int(p), s + 1));
            float p2 = __int_as_float(__builtin_amdgcn_readlane(__float_as_int(p), s + 2));
            float p3 = __int_as_float(__builtin_amdgcn_readlane(__float_as_int(p), s + 3));
            o0 += p0 * vt[i + s][lane];
            o1 += p1 * vt[i + s + 1][lane];
            o2 += p2 * vt[i + s + 2][lane];
            o3 += p3 * vt[i + s + 3][lane];
        }
        float o = (o0 + o1) + (o2 + o3);
        Op[base + (size_t)tg * DMODEL + hcol + lane] = f2bf(o);
    }
}

// ---------------------------------------------------------------- launch
extern "C" void kernel_launch(void* const* d_in, const int* in_sizes, int n_in,
                              void* d_out, int out_size, void* d_ws, size_t ws_size,
                              hipStream_t stream) {
    (void)in_sizes; (void)n_in; (void)out_size; (void)ws_size;
    const float* q = (const float*)d_in[0];
    const float* k = (const float*)d_in[1];
    const float* v = (const float*)d_in[2];
    const float* Wq = (const float*)d_in[3];
    const float* Wk = (const float*)d_in[4];
    const float* Wv = (const float*)d_in[5];
    const float* Wout = (const float*)d_in[6];

    const size_t NBIG = (size_t)MROWS * DMODEL;  // 2,097,152
    const size_t NW = (size_t)DMODEL * DMODEL;   // 262,144
    unsigned short* p = (unsigned short*)d_ws;
    unsigned short* qx = p;  p += NBIG;
    unsigned short* kx = p;  p += NBIG;
    unsigned short* vx = p;  p += NBIG;
    unsigned short* wqx = p; p += NW;
    unsigned short* wkx = p; p += NW;
    unsigned short* wvx = p; p += NW;
    unsigned short* wox = p; p += NW;
    unsigned short* Qp = p;  p += NBIG;
    unsigned short* Kp = p;  p += NBIG;
    unsigned short* Vp = p;  p += NBIG;
    unsigned short* Op = p;

    CvtArgs ca;
    ca.src[0] = q;    ca.dst[0] = qx;  ca.n8[0] = (int)(NBIG / 8);
    ca.src[1] = k;    ca.dst[1] = kx;  ca.n8[1] = (int)(NBIG / 8);
    ca.src[2] = v;    ca.dst[2] = vx;  ca.n8[2] = (int)(NBIG / 8);
    ca.src[3] = Wq;   ca.dst[3] = wqx; ca.n8[3] = (int)(NW / 8);
    ca.src[4] = Wk;   ca.dst[4] = wkx; ca.n8[4] = (int)(NW / 8);
    ca.src[5] = Wv;   ca.dst[5] = wvx; ca.n8[5] = (int)(NW / 8);
    ca.src[6] = Wout; ca.dst[6] = wox; ca.n8[6] = (int)(NW / 8);

    cvt_all<<<dim3((unsigned)(NBIG / 8 / 256), 7), 256, 0, stream>>>(ca);
    gemm_proj<<<dim3(MROWS / GBM, DMODEL / GBN, 3), 256, 0, stream>>>(qx, kx, vx, wqx, wkx, wvx,
                                                                      Qp, Kp, Vp);
    attn_win<<<dim3(SEQ / 64, NH, NB), 256, 0, stream>>>(Qp, Kp, Vp, Op);
    gemm_out<<<dim3(MROWS / GBM, DMODEL / GBN), 256, 0, stream>>>(Op, wox, (float*)d_out);
}

// Round 5
// 121.975 us; speedup vs baseline: 1.2586x; 1.2586x over previous
//
#include <hip/hip_runtime.h>

#define NB 2
#define SEQ 2048
#define NH 8
#define HD 64
#define DMODEL 512
#define WSPAN 64
#define MROWS (NB * SEQ) /* 4096 */

typedef __attribute__((ext_vector_type(4))) float f32x4;
typedef __attribute__((ext_vector_type(4))) int i32x4;
typedef __attribute__((ext_vector_type(8))) short bf16x8;

static __device__ __forceinline__ float bf2f(unsigned short u) {
    return __uint_as_float(((unsigned int)u) << 16);
}
static __device__ __forceinline__ unsigned short f2bf(float f) {
    unsigned int x = __float_as_uint(f);
    x += 0x7fffu + ((x >> 16) & 1u);   // RNE
    return (unsigned short)(x >> 16);
}

// Builtin MFMA: compiler-visible -> hazard nops / waitcnts inserted by backend.
static __device__ __forceinline__ f32x4 mfma16(bf16x8 a, bf16x8 b, f32x4 c) {
    return __builtin_amdgcn_mfma_f32_16x16x32_bf16(a, b, c, 0, 0, 0);
}

// ---------------------------------------------------------------- cvt f32->bf16
struct CvtArgs {
    const float* src[7];
    unsigned short* dst[7];
    int n8[7];
};

__global__ __launch_bounds__(256) void cvt_all(CvtArgs a) {
    const int ai = blockIdx.y;
    const int idx = blockIdx.x * 256 + threadIdx.x;
    if (idx >= a.n8[ai]) return;
    const float* s = a.src[ai] + (size_t)idx * 8;
    float4 f0 = *(const float4*)s;
    float4 f1 = *(const float4*)(s + 4);
    i32x4 o;
    o[0] = (int)((unsigned)f2bf(f0.x) | ((unsigned)f2bf(f0.y) << 16));
    o[1] = (int)((unsigned)f2bf(f0.z) | ((unsigned)f2bf(f0.w) << 16));
    o[2] = (int)((unsigned)f2bf(f1.x) | ((unsigned)f2bf(f1.y) << 16));
    o[3] = (int)((unsigned)f2bf(f1.z) | ((unsigned)f2bf(f1.w) << 16));
    *(i32x4*)(a.dst[ai] + (size_t)idx * 8) = o;
}

// ---------------------------------------------------------------- GEMM (bf16 in, MFMA)
#define GBM 64
#define GBN 128
#define GBK 32
#define GPAD 40   // LDS row stride (bf16 elems): 80B rows -> ~2-way banked b128 reads

template <bool OUT_F32>
static __device__ __forceinline__ void gemm_core(const unsigned short* __restrict__ A,
                                                 const unsigned short* __restrict__ W,
                                                 void* __restrict__ C, int m0, int n0) {
    constexpr int N = DMODEL, K = DMODEL;
    __shared__ __align__(16) unsigned short a_lds[GBM][GPAD];
    __shared__ __align__(16) unsigned short w_lds[GBN][GPAD];
    const int t = threadIdx.x;
    const int lane = t & 63;
    const int wv = t >> 6;
    // staging coords
    const int sa_m = t >> 2;          // 0..63
    const int sa_k = (t & 3) * 8;     // 0,8,16,24
    const int sw_n = t & 127;         // 0..127
    const int sw_k = (t >> 7) * 16;   // 0 or 16
    // fragment coords (verified layout: row/col = lane&15, k = (lane>>4)*8)
    const int fr = lane & 15;
    const int fk = (lane >> 4) * 8;
    const int wm = (wv & 1) * 32;
    const int wn = (wv >> 1) * 64;

    f32x4 acc[2][4];
#pragma unroll
    for (int i = 0; i < 2; ++i)
#pragma unroll
        for (int j = 0; j < 4; ++j) acc[i][j] = (f32x4){0.f, 0.f, 0.f, 0.f};

    for (int k0 = 0; k0 < K; k0 += GBK) {
        // A chunk: 8 contiguous bf16 per thread
        i32x4 av = *(const i32x4*)(A + (size_t)(m0 + sa_m) * K + k0 + sa_k);
        // W chunk: 16 k-strided bf16 per thread (transposed into LDS as W^T)
        const unsigned short* wp = W + (size_t)(k0 + sw_k) * N + n0 + sw_n;
        unsigned int ww[8];
#pragma unroll
        for (int j2 = 0; j2 < 8; ++j2) {
            unsigned int lo = wp[(size_t)(2 * j2) * N];
            unsigned int hi = wp[(size_t)(2 * j2 + 1) * N];
            ww[j2] = (lo & 0xffffu) | (hi << 16);
        }
        i32x4 w0 = {(int)ww[0], (int)ww[1], (int)ww[2], (int)ww[3]};
        i32x4 w1 = {(int)ww[4], (int)ww[5], (int)ww[6], (int)ww[7]};
        __syncthreads();
        *(i32x4*)&a_lds[sa_m][sa_k] = av;
        *(i32x4*)&w_lds[sw_n][sw_k] = w0;
        *(i32x4*)&w_lds[sw_n][sw_k + 8] = w1;
        __syncthreads();
        bf16x8 af0 = *(const bf16x8*)&a_lds[wm + fr][fk];
        bf16x8 af1 = *(const bf16x8*)&a_lds[wm + 16 + fr][fk];
#pragma unroll
        for (int ni = 0; ni < 4; ++ni) {
            bf16x8 bfr = *(const bf16x8*)&w_lds[wn + ni * 16 + fr][fk];
            acc[0][ni] = mfma16(af0, bfr, acc[0][ni]);
            acc[1][ni] = mfma16(af1, bfr, acc[1][ni]);
        }
    }
#pragma unroll
    for (int mi = 0; mi < 2; ++mi) {
#pragma unroll
        for (int ni = 0; ni < 4; ++ni) {
#pragma unroll
            for (int r = 0; r < 4; ++r) {
                const int row = m0 + wm + mi * 16 + (lane >> 4) * 4 + r;
                const int col = n0 + wn + ni * 16 + fr;
                if constexpr (OUT_F32)
                    ((float*)C)[(size_t)row * N + col] = acc[mi][ni][r];
                else
                    ((unsigned short*)C)[(size_t)row * N + col] = f2bf(acc[mi][ni][r]);
            }
        }
    }
}

__global__ __launch_bounds__(256) void gemm_proj(
    const unsigned short* __restrict__ qx, const unsigned short* __restrict__ kx,
    const unsigned short* __restrict__ vx, const unsigned short* __restrict__ wqx,
    const unsigned short* __restrict__ wkx, const unsigned short* __restrict__ wvx,
    unsigned short* __restrict__ Qp, unsigned short* __restrict__ Kp,
    unsigned short* __restrict__ Vp) {
    const unsigned short* A;
    const unsigned short* W;
    unsigned short* C;
    if (blockIdx.z == 0) { A = qx; W = wqx; C = Qp; }
    else if (blockIdx.z == 1) { A = kx; W = wkx; C = Kp; }
    else { A = vx; W = wvx; C = Vp; }
    gemm_core<false>(A, W, C, blockIdx.x * GBM, blockIdx.y * GBN);
}

__global__ __launch_bounds__(256) void gemm_out(const unsigned short* __restrict__ Op,
                                                const unsigned short* __restrict__ wox,
                                                float* __restrict__ out) {
    gemm_core<true>(Op, wox, out, blockIdx.x * GBM, blockIdx.y * GBN);
}

// ---------------------------------------------------------------- windowed attention (MFMA)
// grid: (SEQ/64, NH, NB); 4 waves; wave qg owns queries [16qg,16qg+16).
// Window keys local l in [0,128): global j = t0-63+l. Query local i needs l in [i, i+63].
// Wave qg uses key 16-blocks kbg = qg..qg+4 (80 keys) -> 10 QK MFMAs, 12 PV MFMAs.
// kt [128][64] bf16 XOR-swz (granule ^= key&7); vT [64][128] bf16 XOR-swz (granule ^= d&15).
__global__ __launch_bounds__(256) void attn_win(const unsigned short* __restrict__ Qp,
                                                const unsigned short* __restrict__ Kp,
                                                const unsigned short* __restrict__ Vp,
                                                unsigned short* __restrict__ Op) {
    __shared__ __align__(16) unsigned short kt[128 * 64];   // 16 KB
    __shared__ __align__(16) unsigned short vT[64 * 128];   // 16 KB
    __shared__ __align__(16) unsigned short pw[4][16][104]; // 13 KB, per-wave P [q][ks]
    const int tile = blockIdx.x, h = blockIdx.y, b = blockIdx.z;
    const int t0 = tile * 64;
    const int tid = threadIdx.x;
    const int lane = tid & 63;
    const int qg = tid >> 6;        // wave id = query group
    const int c = lane & 15;
    const int g = lane >> 4;
    const int hcol = h * HD;
    const size_t base = (size_t)b * SEQ * DMODEL;

    // ---- stage K window (swizzled row-major) + V window (transposed, swizzled)
    {
        const int l = tid >> 1;             // 0..127
        const int dh = (tid & 1) * 32;      // dim half
        int j = t0 - (WSPAN - 1) + l;
        int jc = j < 0 ? 0 : (j > SEQ - 1 ? SEQ - 1 : j);  // clamped rows fully masked
        const unsigned short* kp = Kp + base + (size_t)jc * DMODEL + hcol + dh;
        const unsigned short* vp = Vp + base + (size_t)jc * DMODEL + hcol + dh;
        const int lg = (l & 7) << 4;
#pragma unroll
        for (int u = 0; u < 4; ++u) {
            const int dg = dh + u * 8;
            i32x4 kv = *(const i32x4*)(kp + u * 8);
            i32x4 vv = *(const i32x4*)(vp + u * 8);
            *(i32x4*)((char*)kt + l * 128 + ((dg * 2) ^ lg)) = kv;
#pragma unroll
            for (int e2 = 0; e2 < 4; ++e2) {
                unsigned int w2 = (unsigned int)vv[e2];
                const int d0 = dg + 2 * e2, d1 = d0 + 1;
                *(unsigned short*)((char*)vT + d0 * 256 + ((((l >> 3) ^ (d0 & 15)) << 4)) +
                                   (l & 7) * 2) = (unsigned short)(w2 & 0xffffu);
                *(unsigned short*)((char*)vT + d1 * 256 + ((((l >> 3) ^ (d1 & 15)) << 4)) +
                                   (l & 7) * 2) = (unsigned short)(w2 >> 16);
            }
        }
    }
    // zero P pad region ks in [80,96) (keeps PV K=96 exact)
    *(unsigned long long*)&pw[qg][lane >> 2][80 + (lane & 3) * 4] = 0ull;
    __syncthreads();

    // ---- QK^T: A = Q (direct global), B = K blocks from kt
    const unsigned short* qrow =
        Qp + base + (size_t)(t0 + 16 * qg + c) * DMODEL + hcol + 8 * g;
    const bf16x8 qa0 = *(const bf16x8*)qrow;
    const bf16x8 qa1 = *(const bf16x8*)(qrow + 32);
    f32x4 sacc[5];
#pragma unroll
    for (int kb = 0; kb < 5; ++kb) {
        sacc[kb] = (f32x4){0.f, 0.f, 0.f, 0.f};
        const int key = 16 * (qg + kb) + c;
        const int sw = (key & 7) << 4;
        bf16x8 kf0 = *(const bf16x8*)((const char*)kt + key * 128 + ((16 * g) ^ sw));
        bf16x8 kf1 = *(const bf16x8*)((const char*)kt + key * 128 + ((64 + 16 * g) ^ sw));
        sacc[kb] = mfma16(qa0, kf0, sacc[kb]);
        sacc[kb] = mfma16(qa1, kf1, sacc[kb]);
    }

    // ---- softmax in-register; C layout: col=c=key-in-block, row=4g+r=query-in-group
    const int L0 = 63 - t0;  // j>=0  <=>  l >= L0 (only binds in tile 0)
#pragma unroll
    for (int r = 0; r < 4; ++r) {
        const int iq = 4 * g + r;
        float sv[5];
        float m = -3e38f;
#pragma unroll
        for (int kb = 0; kb < 5; ++kb) {
            float x = sacc[kb][r] * 0.125f;  // 1/sqrt(64)
            const int dlk = 16 * kb + c - iq;              // l - i
            const int l = 16 * (qg + kb) + c;
            x = (dlk >= 0 && dlk <= 63 && l >= L0) ? x : -3e38f;
            sv[kb] = x;
            m = fmaxf(m, x);
        }
#pragma unroll
        for (int off = 1; off <= 8; off <<= 1) m = fmaxf(m, __shfl_xor(m, off));
        float s = 0.f;
#pragma unroll
        for (int kb = 0; kb < 5; ++kb) {
            float pp = __expf(sv[kb] - m);
            sv[kb] = pp;
            s += pp;
        }
#pragma unroll
        for (int off = 1; off <= 8; off <<= 1) s += __shfl_xor(s, off);
        const float rinv = 1.0f / s;
#pragma unroll
        for (int kb = 0; kb < 5; ++kb)
            pw[qg][iq][16 * kb + c] = f2bf(sv[kb] * rinv);
    }

    // ---- PV: A = P[16x32] from pw, B = V^T blocks from vT
    f32x4 oacc[4];
#pragma unroll
    for (int nb = 0; nb < 4; ++nb) oacc[nb] = (f32x4){0.f, 0.f, 0.f, 0.f};
#pragma unroll
    for (int ks = 0; ks < 3; ++ks) {
        const bf16x8 pa = *(const bf16x8*)&pw[qg][c][ks * 32 + 8 * g];
        const int lbase = 16 * qg + ks * 32 + 8 * g;
        // &15 clamp: lanes whose keys exceed the 128-key window read valid (wrong-but-
        // finite) vT data; their P is zero, so the product is exactly 0.
        const int gran = ((lbase >> 3) & 15) ^ c;
#pragma unroll
        for (int nb = 0; nb < 4; ++nb) {
            const bf16x8 vf =
                *(const bf16x8*)((const char*)vT + (16 * nb + c) * 256 + (gran << 4));
            oacc[nb] = mfma16(pa, vf, oacc[nb]);
        }
    }

    // ---- epilogue: C layout col=c (dim in block), row=4g+jr (query in group)
    unsigned short* orow = Op + base + (size_t)(t0 + 16 * qg + 4 * g) * DMODEL + hcol + c;
#pragma unroll
    for (int nb = 0; nb < 4; ++nb)
#pragma unroll
        for (int jr = 0; jr < 4; ++jr)
            orow[(size_t)jr * DMODEL + 16 * nb] = f2bf(oacc[nb][jr]);
}

// ---------------------------------------------------------------- launch
extern "C" void kernel_launch(void* const* d_in, const int* in_sizes, int n_in,
                              void* d_out, int out_size, void* d_ws, size_t ws_size,
                              hipStream_t stream) {
    (void)in_sizes; (void)n_in; (void)out_size; (void)ws_size;
    const float* q = (const float*)d_in[0];
    const float* k = (const float*)d_in[1];
    const float* v = (const float*)d_in[2];
    const float* Wq = (const float*)d_in[3];
    const float* Wk = (const float*)d_in[4];
    const float* Wv = (const float*)d_in[5];
    const float* Wout = (const float*)d_in[6];

    const size_t NBIG = (size_t)MROWS * DMODEL;  // 2,097,152
    const size_t NW = (size_t)DMODEL * DMODEL;   // 262,144
    unsigned short* p = (unsigned short*)d_ws;
    unsigned short* qx = p;  p += NBIG;
    unsigned short* kx = p;  p += NBIG;
    unsigned short* vx = p;  p += NBIG;
    unsigned short* wqx = p; p += NW;
    unsigned short* wkx = p; p += NW;
    unsigned short* wvx = p; p += NW;
    unsigned short* wox = p; p += NW;
    unsigned short* Qp = p;  p += NBIG;
    unsigned short* Kp = p;  p += NBIG;
    unsigned short* Vp = p;  p += NBIG;
    unsigned short* Op = p;

    CvtArgs ca;
    ca.src[0] = q;    ca.dst[0] = qx;  ca.n8[0] = (int)(NBIG / 8);
    ca.src[1] = k;    ca.dst[1] = kx;  ca.n8[1] = (int)(NBIG / 8);
    ca.src[2] = v;    ca.dst[2] = vx;  ca.n8[2] = (int)(NBIG / 8);
    ca.src[3] = Wq;   ca.dst[3] = wqx; ca.n8[3] = (int)(NW / 8);
    ca.src[4] = Wk;   ca.dst[4] = wkx; ca.n8[4] = (int)(NW / 8);
    ca.src[5] = Wv;   ca.dst[5] = wvx; ca.n8[5] = (int)(NW / 8);
    ca.src[6] = Wout; ca.dst[6] = wox; ca.n8[6] = (int)(NW / 8);

    cvt_all<<<dim3((unsigned)(NBIG / 8 / 256), 7), 256, 0, stream>>>(ca);
    gemm_proj<<<dim3(MROWS / GBM, DMODEL / GBN, 3), 256, 0, stream>>>(qx, kx, vx, wqx, wkx, wvx,
                                                                      Qp, Kp, Vp);
    attn_win<<<dim3(SEQ / 64, NH, NB), 256, 0, stream>>>(Qp, Kp, Vp, Op);
    gemm_out<<<dim3(MROWS / GBM, DMODEL / GBN), 256, 0, stream>>>(Op, wox, (float*)d_out);
}

// Round 7
// 121.133 us; speedup vs baseline: 1.2674x; 1.0070x over previous
//
#include <hip/hip_runtime.h>

#define NB 2
#define SEQ 2048
#define NH 8
#define HD 64
#define DMODEL 512
#define WSPAN 64
#define MROWS (NB * SEQ) /* 4096 */

typedef __attribute__((ext_vector_type(4))) float f32x4;
typedef __attribute__((ext_vector_type(4))) int i32x4;
typedef __attribute__((ext_vector_type(8))) short bf16x8;

static __device__ __forceinline__ float bf2f(unsigned short u) {
    return __uint_as_float(((unsigned int)u) << 16);
}
static __device__ __forceinline__ unsigned short f2bf(float f) {
    unsigned int x = __float_as_uint(f);
    x += 0x7fffu + ((x >> 16) & 1u);   // RNE
    return (unsigned short)(x >> 16);
}

// Builtin MFMA: compiler-visible -> hazard nops / waitcnts inserted by backend.
static __device__ __forceinline__ f32x4 mfma16(bf16x8 a, bf16x8 b, f32x4 c) {
    return __builtin_amdgcn_mfma_f32_16x16x32_bf16(a, b, c, 0, 0, 0);
}

// ---------------------------------------------------------------- cvt f32->bf16 (3 big inputs)
struct Cvt3 {
    const float* src[3];
    unsigned short* dst[3];
};

__global__ __launch_bounds__(256) void cvt_big(Cvt3 a) {
    const int ai = blockIdx.y;
    const int idx = blockIdx.x * 256 + threadIdx.x;
    const float* s = a.src[ai] + (size_t)idx * 8;
    float4 f0 = *(const float4*)s;
    float4 f1 = *(const float4*)(s + 4);
    i32x4 o;
    o[0] = (int)((unsigned)f2bf(f0.x) | ((unsigned)f2bf(f0.y) << 16));
    o[1] = (int)((unsigned)f2bf(f0.z) | ((unsigned)f2bf(f0.w) << 16));
    o[2] = (int)((unsigned)f2bf(f1.x) | ((unsigned)f2bf(f1.y) << 16));
    o[3] = (int)((unsigned)f2bf(f1.z) | ((unsigned)f2bf(f1.w) << 16));
    *(i32x4*)(a.dst[ai] + (size_t)idx * 8) = o;
}

// ---------------------------------------------------------------- weight cvt + transpose
// W [K=512][N=512] f32 -> WT [N][K] bf16, via 64x64 LDS tiles. grid (8,8,4).
struct Wt4 {
    const float* src[4];
    unsigned short* dst[4];
};

__global__ __launch_bounds__(256) void cvt_wT(Wt4 a) {
    __shared__ unsigned short t64[64][72];  // pad 8 -> write/read banks spread
    const int w = blockIdx.z;
    const float* src = a.src[w];
    unsigned short* dst = a.dst[w];
    const int k0 = blockIdx.x * 64, n0 = blockIdx.y * 64;
    const int t = threadIdx.x;
    const int r = t >> 2;             // 0..63
    const int cg = (t & 3) * 16;      // 0,16,32,48
    const float* sp = src + (size_t)(k0 + r) * DMODEL + n0 + cg;
#pragma unroll
    for (int j = 0; j < 16; j += 4) {
        float4 f = *(const float4*)(sp + j);
        t64[r][cg + j + 0] = f2bf(f.x);
        t64[r][cg + j + 1] = f2bf(f.y);
        t64[r][cg + j + 2] = f2bf(f.z);
        t64[r][cg + j + 3] = f2bf(f.w);
    }
    __syncthreads();
    unsigned short buf[16];
#pragma unroll
    for (int j = 0; j < 16; ++j) buf[j] = t64[cg + j][r];
    unsigned short* dp = dst + (size_t)(n0 + r) * DMODEL + k0 + cg;
    *(i32x4*)dp = *(const i32x4*)buf;
    *(i32x4*)(dp + 8) = *(const i32x4*)(buf + 8);
}

// ---------------------------------------------------------------- GEMM (A row-K, BT row-K)
#define TBM 128
#define TBN 128
#define TBK 32
#define LPAD 40   // 80B rows: fragment b128 reads land on 8 even banks x 4 -> floor

template <bool OUT_F32>
static __device__ __forceinline__ void gemm_core(const unsigned short* __restrict__ A,
                                                 const unsigned short* __restrict__ BT,
                                                 void* __restrict__ C, int m0, int n0) {
    constexpr int N = DMODEL, K = DMODEL;
    __shared__ __align__(16) unsigned short a_lds[TBM][LPAD];
    __shared__ __align__(16) unsigned short b_lds[TBN][LPAD];
    const int t = threadIdx.x;
    const int lane = t & 63;
    const int wv = t >> 6;
    // staging coords: thread t loads 16 contiguous bf16 of row t>>1
    const int s_r = t >> 1;           // 0..127
    const int s_k = (t & 1) * 16;     // 0 or 16
    // fragment coords (verified layout: row/col = lane&15, k = (lane>>4)*8)
    const int fr = lane & 15;
    const int fk = (lane >> 4) * 8;
    const int wm = (wv & 1) * 64;
    const int wn = (wv >> 1) * 64;

    f32x4 acc[4][4];
#pragma unroll
    for (int i = 0; i < 4; ++i)
#pragma unroll
        for (int j = 0; j < 4; ++j) acc[i][j] = (f32x4){0.f, 0.f, 0.f, 0.f};

    for (int k0 = 0; k0 < K; k0 += TBK) {
        const unsigned short* ap = A + (size_t)(m0 + s_r) * K + k0 + s_k;
        const unsigned short* bp = BT + (size_t)(n0 + s_r) * K + k0 + s_k;
        i32x4 av0 = *(const i32x4*)ap;
        i32x4 av1 = *(const i32x4*)(ap + 8);
        i32x4 bv0 = *(const i32x4*)bp;
        i32x4 bv1 = *(const i32x4*)(bp + 8);
        __syncthreads();
        *(i32x4*)&a_lds[s_r][s_k] = av0;
        *(i32x4*)&a_lds[s_r][s_k + 8] = av1;
        *(i32x4*)&b_lds[s_r][s_k] = bv0;
        *(i32x4*)&b_lds[s_r][s_k + 8] = bv1;
        __syncthreads();
        bf16x8 af[4], bf[4];
#pragma unroll
        for (int i = 0; i < 4; ++i) {
            af[i] = *(const bf16x8*)&a_lds[wm + i * 16 + fr][fk];
            bf[i] = *(const bf16x8*)&b_lds[wn + i * 16 + fr][fk];
        }
#pragma unroll
        for (int mi = 0; mi < 4; ++mi)
#pragma unroll
            for (int ni = 0; ni < 4; ++ni) acc[mi][ni] = mfma16(af[mi], bf[ni], acc[mi][ni]);
    }
#pragma unroll
    for (int mi = 0; mi < 4; ++mi) {
#pragma unroll
        for (int ni = 0; ni < 4; ++ni) {
#pragma unroll
            for (int r = 0; r < 4; ++r) {
                const int row = m0 + wm + mi * 16 + (lane >> 4) * 4 + r;
                const int col = n0 + wn + ni * 16 + fr;
                if constexpr (OUT_F32)
                    ((float*)C)[(size_t)row * N + col] = acc[mi][ni][r];
                else
                    ((unsigned short*)C)[(size_t)row * N + col] = f2bf(acc[mi][ni][r]);
            }
        }
    }
}

__global__ __launch_bounds__(256) void gemm_proj(
    const unsigned short* __restrict__ qx, const unsigned short* __restrict__ kx,
    const unsigned short* __restrict__ vx, const unsigned short* __restrict__ wtq,
    const unsigned short* __restrict__ wtk, const unsigned short* __restrict__ wtv,
    unsigned short* __restrict__ Qp, unsigned short* __restrict__ Kp,
    unsigned short* __restrict__ Vp) {
    const unsigned short* A;
    const unsigned short* W;
    unsigned short* C;
    if (blockIdx.z == 0) { A = qx; W = wtq; C = Qp; }
    else if (blockIdx.z == 1) { A = kx; W = wtk; C = Kp; }
    else { A = vx; W = wtv; C = Vp; }
    gemm_core<false>(A, W, C, blockIdx.x * TBM, blockIdx.y * TBN);
}

__global__ __launch_bounds__(256) void gemm_out(const unsigned short* __restrict__ Op,
                                                const unsigned short* __restrict__ wto,
                                                float* __restrict__ out) {
    gemm_core<true>(Op, wto, out, blockIdx.x * TBM, blockIdx.y * TBN);
}

// ---------------------------------------------------------------- windowed attention (MFMA)
// grid: (SEQ/64, NH, NB); 4 waves; wave qg owns queries [16qg,16qg+16).
// Window keys local l in [0,128): global j = t0-63+l. Query local i needs l in [i, i+63].
// Wave qg uses key 16-blocks kbg = qg..qg+4 (80 keys) -> 10 QK MFMAs, 12 PV MFMAs.
// kt [128][64] bf16 XOR-swz (granule ^= key&7); vT [64][128] bf16 XOR-swz (granule ^= d&15).
__global__ __launch_bounds__(256) void attn_win(const unsigned short* __restrict__ Qp,
                                                const unsigned short* __restrict__ Kp,
                                                const unsigned short* __restrict__ Vp,
                                                unsigned short* __restrict__ Op) {
    __shared__ __align__(16) unsigned short kt[128 * 64];   // 16 KB
    __shared__ __align__(16) unsigned short vT[64 * 128];   // 16 KB
    __shared__ __align__(16) unsigned short pw[4][16][104]; // 13 KB, per-wave P [q][ks]
    const int tile = blockIdx.x, h = blockIdx.y, b = blockIdx.z;
    const int t0 = tile * 64;
    const int tid = threadIdx.x;
    const int lane = tid & 63;
    const int qg = tid >> 6;        // wave id = query group
    const int c = lane & 15;
    const int g = lane >> 4;
    const int hcol = h * HD;
    const size_t base = (size_t)b * SEQ * DMODEL;

    // ---- stage K window (swizzled row-major) + V window (transposed, swizzled)
    {
        const int l = tid >> 1;             // 0..127
        const int dh = (tid & 1) * 32;      // dim half
        int j = t0 - (WSPAN - 1) + l;
        int jc = j < 0 ? 0 : (j > SEQ - 1 ? SEQ - 1 : j);  // clamped rows fully masked
        const unsigned short* kp = Kp + base + (size_t)jc * DMODEL + hcol + dh;
        const unsigned short* vp = Vp + base + (size_t)jc * DMODEL + hcol + dh;
        const int lg = (l & 7) << 4;
#pragma unroll
        for (int u = 0; u < 4; ++u) {
            const int dg = dh + u * 8;
            i32x4 kv = *(const i32x4*)(kp + u * 8);
            i32x4 vv = *(const i32x4*)(vp + u * 8);
            *(i32x4*)((char*)kt + l * 128 + ((dg * 2) ^ lg)) = kv;
#pragma unroll
            for (int e2 = 0; e2 < 4; ++e2) {
                unsigned int w2 = (unsigned int)vv[e2];
                const int d0 = dg + 2 * e2, d1 = d0 + 1;
                *(unsigned short*)((char*)vT + d0 * 256 + ((((l >> 3) ^ (d0 & 15)) << 4)) +
                                   (l & 7) * 2) = (unsigned short)(w2 & 0xffffu);
                *(unsigned short*)((char*)vT + d1 * 256 + ((((l >> 3) ^ (d1 & 15)) << 4)) +
                                   (l & 7) * 2) = (unsigned short)(w2 >> 16);
            }
        }
    }
    // zero P pad region ks in [80,96) (keeps PV K=96 exact)
    *(unsigned long long*)&pw[qg][lane >> 2][80 + (lane & 3) * 4] = 0ull;
    __syncthreads();

    // ---- QK^T: A = Q (direct global), B = K blocks from kt
    const unsigned short* qrow =
        Qp + base + (size_t)(t0 + 16 * qg + c) * DMODEL + hcol + 8 * g;
    const bf16x8 qa0 = *(const bf16x8*)qrow;
    const bf16x8 qa1 = *(const bf16x8*)(qrow + 32);
    f32x4 sacc[5];
#pragma unroll
    for (int kb = 0; kb < 5; ++kb) {
        sacc[kb] = (f32x4){0.f, 0.f, 0.f, 0.f};
        const int key = 16 * (qg + kb) + c;
        const int sw = (key & 7) << 4;
        bf16x8 kf0 = *(const bf16x8*)((const char*)kt + key * 128 + ((16 * g) ^ sw));
        bf16x8 kf1 = *(const bf16x8*)((const char*)kt + key * 128 + ((64 + 16 * g) ^ sw));
        sacc[kb] = mfma16(qa0, kf0, sacc[kb]);
        sacc[kb] = mfma16(qa1, kf1, sacc[kb]);
    }

    // ---- softmax in-register; C layout: col=c=key-in-block, row=4g+r=query-in-group
    const int L0 = 63 - t0;  // j>=0  <=>  l >= L0 (only binds in tile 0)
#pragma unroll
    for (int r = 0; r < 4; ++r) {
        const int iq = 4 * g + r;
        float sv[5];
        float m = -3e38f;
#pragma unroll
        for (int kb = 0; kb < 5; ++kb) {
            float x = sacc[kb][r] * 0.125f;  // 1/sqrt(64)
            const int dlk = 16 * kb + c - iq;              // l - i
            const int l = 16 * (qg + kb) + c;
            x = (dlk >= 0 && dlk <= 63 && l >= L0) ? x : -3e38f;
            sv[kb] = x;
            m = fmaxf(m, x);
        }
#pragma unroll
        for (int off = 1; off <= 8; off <<= 1) m = fmaxf(m, __shfl_xor(m, off));
        float s = 0.f;
#pragma unroll
        for (int kb = 0; kb < 5; ++kb) {
            float pp = __expf(sv[kb] - m);
            sv[kb] = pp;
            s += pp;
        }
#pragma unroll
        for (int off = 1; off <= 8; off <<= 1) s += __shfl_xor(s, off);
        const float rinv = 1.0f / s;
#pragma unroll
        for (int kb = 0; kb < 5; ++kb)
            pw[qg][iq][16 * kb + c] = f2bf(sv[kb] * rinv);
    }

    // ---- PV: A = P[16x32] from pw, B = V^T blocks from vT
    f32x4 oacc[4];
#pragma unroll
    for (int nb = 0; nb < 4; ++nb) oacc[nb] = (f32x4){0.f, 0.f, 0.f, 0.f};
#pragma unroll
    for (int ks = 0; ks < 3; ++ks) {
        const bf16x8 pa = *(const bf16x8*)&pw[qg][c][ks * 32 + 8 * g];
        const int lbase = 16 * qg + ks * 32 + 8 * g;
        // &15 clamp: lanes whose keys exceed the 128-key window read valid (wrong-but-
        // finite) vT data; their P is zero, so the product is exactly 0.
        const int gran = ((lbase >> 3) & 15) ^ c;
#pragma unroll
        for (int nb = 0; nb < 4; ++nb) {
            const bf16x8 vf =
                *(const bf16x8*)((const char*)vT + (16 * nb + c) * 256 + (gran << 4));
            oacc[nb] = mfma16(pa, vf, oacc[nb]);
        }
    }

    // ---- epilogue: C layout col=c (dim in block), row=4g+jr (query in group)
    unsigned short* orow = Op + base + (size_t)(t0 + 16 * qg + 4 * g) * DMODEL + hcol + c;
#pragma unroll
    for (int nb = 0; nb < 4; ++nb)
#pragma unroll
        for (int jr = 0; jr < 4; ++jr)
            orow[(size_t)jr * DMODEL + 16 * nb] = f2bf(oacc[nb][jr]);
}

// ---------------------------------------------------------------- launch
extern "C" void kernel_launch(void* const* d_in, const int* in_sizes, int n_in,
                              void* d_out, int out_size, void* d_ws, size_t ws_size,
                              hipStream_t stream) {
    (void)in_sizes; (void)n_in; (void)out_size; (void)ws_size;
    const float* q = (const float*)d_in[0];
    const float* k = (const float*)d_in[1];
    const float* v = (const float*)d_in[2];
    const float* Wq = (const float*)d_in[3];
    const float* Wk = (const float*)d_in[4];
    const float* Wv = (const float*)d_in[5];
    const float* Wout = (const float*)d_in[6];

    const size_t NBIG = (size_t)MROWS * DMODEL;  // 2,097,152
    const size_t NW = (size_t)DMODEL * DMODEL;   // 262,144
    unsigned short* p = (unsigned short*)d_ws;
    unsigned short* qx = p;  p += NBIG;
    unsigned short* kx = p;  p += NBIG;
    unsigned short* vx = p;  p += NBIG;
    unsigned short* wtq = p; p += NW;   // transposed [N][K]
    unsigned short* wtk = p; p += NW;
    unsigned short* wtv = p; p += NW;
    unsigned short* wto = p; p += NW;
    unsigned short* Qp = p;  p += NBIG;
    unsigned short* Kp = p;  p += NBIG;
    unsigned short* Vp = p;  p += NBIG;
    unsigned short* Op = p;

    Cvt3 c3;
    c3.src[0] = q; c3.dst[0] = qx;
    c3.src[1] = k; c3.dst[1] = kx;
    c3.src[2] = v; c3.dst[2] = vx;
    Wt4 w4;
    w4.src[0] = Wq;   w4.dst[0] = wtq;
    w4.src[1] = Wk;   w4.dst[1] = wtk;
    w4.src[2] = Wv;   w4.dst[2] = wtv;
    w4.src[3] = Wout; w4.dst[3] = wto;

    cvt_big<<<dim3((unsigned)(NBIG / 8 / 256), 3), 256, 0, stream>>>(c3);
    cvt_wT<<<dim3(8, 8, 4), 256, 0, stream>>>(w4);
    gemm_proj<<<dim3(MROWS / TBM, DMODEL / TBN, 3), 256, 0, stream>>>(qx, kx, vx, wtq, wtk, wtv,
                                                                      Qp, Kp, Vp);
    attn_win<<<dim3(SEQ / 64, NH, NB), 256, 0, stream>>>(Qp, Kp, Vp, Op);
    gemm_out<<<dim3(MROWS / TBM, DMODEL / TBN), 256, 0, stream>>>(Op, wto, (float*)d_out);
}

// Round 10
// 117.049 us; speedup vs baseline: 1.3116x; 1.0349x over previous
//
#include <hip/hip_runtime.h>

#define NB 2
#define SEQ 2048
#define NH 8
#define HD 64
#define DMODEL 512
#define WSPAN 64
#define MROWS (NB * SEQ) /* 4096 */

typedef __attribute__((ext_vector_type(4))) float f32x4;
typedef __attribute__((ext_vector_type(4))) int i32x4;
typedef __attribute__((ext_vector_type(8))) short bf16x8;

static __device__ __forceinline__ float bf2f(unsigned short u) {
    return __uint_as_float(((unsigned int)u) << 16);
}
static __device__ __forceinline__ unsigned short f2bf(float f) {
    unsigned int x = __float_as_uint(f);
    x += 0x7fffu + ((x >> 16) & 1u);   // RNE
    return (unsigned short)(x >> 16);
}
static __device__ __forceinline__ int pk2(float x, float y) {
    return (int)(((unsigned)f2bf(x)) | ((unsigned)f2bf(y) << 16));
}

// Builtin MFMA: compiler-visible -> hazard nops / waitcnts inserted by backend.
static __device__ __forceinline__ f32x4 mfma16(bf16x8 a, bf16x8 b, f32x4 c) {
    return __builtin_amdgcn_mfma_f32_16x16x32_bf16(a, b, c, 0, 0, 0);
}

// ---------------------------------------------------------------- weight cvt + transpose
// W [K=512][N=512] f32 -> WT [N][K] bf16, via 64x64 LDS tiles. grid (8,8,4).
struct Wt4 {
    const float* src[4];
    unsigned short* dst[4];
};

__global__ __launch_bounds__(256) void cvt_wT(Wt4 a) {
    __shared__ unsigned short t64[64][72];  // pad 8 -> write/read banks spread
    const int w = blockIdx.z;
    const float* src = a.src[w];
    unsigned short* dst = a.dst[w];
    const int k0 = blockIdx.x * 64, n0 = blockIdx.y * 64;
    const int t = threadIdx.x;
    const int r = t >> 2;             // 0..63
    const int cg = (t & 3) * 16;      // 0,16,32,48
    const float* sp = src + (size_t)(k0 + r) * DMODEL + n0 + cg;
#pragma unroll
    for (int j = 0; j < 16; j += 4) {
        float4 f = *(const float4*)(sp + j);
        t64[r][cg + j + 0] = f2bf(f.x);
        t64[r][cg + j + 1] = f2bf(f.y);
        t64[r][cg + j + 2] = f2bf(f.z);
        t64[r][cg + j + 3] = f2bf(f.w);
    }
    __syncthreads();
    unsigned short buf[16];
#pragma unroll
    for (int j = 0; j < 16; ++j) buf[j] = t64[cg + j][r];
    unsigned short* dp = dst + (size_t)(n0 + r) * DMODEL + k0 + cg;
    *(i32x4*)dp = *(const i32x4*)buf;
    *(i32x4*)(dp + 8) = *(const i32x4*)(buf + 8);
}

// ---------------------------------------------------------------- GEMM (A row-K f32|bf16, BT row-K bf16)
#define TBM 128
#define TBN 128
#define TBK 32
#define LPAD 40   // 80B rows: fragment b128 reads -> 2-way max (free)

template <bool A_F32, bool OUT_F32>
static __device__ __forceinline__ void gemm_core(const void* __restrict__ Av,
                                                 const unsigned short* __restrict__ BT,
                                                 void* __restrict__ C, int m0, int n0) {
    constexpr int N = DMODEL, K = DMODEL;
    constexpr int NSTEP = K / TBK;  // 16
    __shared__ __align__(16) unsigned short a_lds[TBM][LPAD];
    __shared__ __align__(16) unsigned short b_lds[TBN][LPAD];
    const int t = threadIdx.x;
    const int lane = t & 63;
    const int wv = t >> 6;
    // staging coords: thread t stages 16 contiguous elems of row t>>1
    const int s_r = t >> 1;           // 0..127
    const int s_k = (t & 1) * 16;     // 0 or 16
    // fragment coords (verified layout: row/col = lane&15, k = (lane>>4)*8)
    const int fr = lane & 15;
    const int fk = (lane >> 4) * 8;
    const int wm = (wv & 1) * 64;
    const int wn = (wv >> 1) * 64;

    f32x4 acc[4][4];
#pragma unroll
    for (int i = 0; i < 4; ++i)
#pragma unroll
        for (int j = 0; j < 4; ++j) acc[i][j] = (f32x4){0.f, 0.f, 0.f, 0.f};

    i32x4 a0, a1, b0, b1;
    auto load_ab = [&](int k0) {
        if constexpr (A_F32) {
            const float* ap = (const float*)Av + (size_t)(m0 + s_r) * K + k0 + s_k;
            float4 f0 = *(const float4*)ap;
            float4 f1 = *(const float4*)(ap + 4);
            float4 f2 = *(const float4*)(ap + 8);
            float4 f3 = *(const float4*)(ap + 12);
            a0 = (i32x4){pk2(f0.x, f0.y), pk2(f0.z, f0.w), pk2(f1.x, f1.y), pk2(f1.z, f1.w)};
            a1 = (i32x4){pk2(f2.x, f2.y), pk2(f2.z, f2.w), pk2(f3.x, f3.y), pk2(f3.z, f3.w)};
        } else {
            const unsigned short* ap =
                (const unsigned short*)Av + (size_t)(m0 + s_r) * K + k0 + s_k;
            a0 = *(const i32x4*)ap;
            a1 = *(const i32x4*)(ap + 8);
        }
        const unsigned short* bp = BT + (size_t)(n0 + s_r) * K + k0 + s_k;
        b0 = *(const i32x4*)bp;
        b1 = *(const i32x4*)(bp + 8);
    };

    load_ab(0);
    for (int ks = 0; ks < NSTEP; ++ks) {
        __syncthreads();   // previous step's fragment reads complete
        *(i32x4*)&a_lds[s_r][s_k] = a0;
        *(i32x4*)&a_lds[s_r][s_k + 8] = a1;
        *(i32x4*)&b_lds[s_r][s_k] = b0;
        *(i32x4*)&b_lds[s_r][s_k + 8] = b1;
        __syncthreads();   // LDS visible
        // issue next-tile global loads; latency hides under the MFMA cluster
        const int kn = (ks + 1 < NSTEP) ? (ks + 1) * TBK : ks * TBK;
        load_ab(kn);
        bf16x8 af[4], bf[4];
#pragma unroll
        for (int i = 0; i < 4; ++i) {
            af[i] = *(const bf16x8*)&a_lds[wm + i * 16 + fr][fk];
            bf[i] = *(const bf16x8*)&b_lds[wn + i * 16 + fr][fk];
        }
#pragma unroll
        for (int mi = 0; mi < 4; ++mi)
#pragma unroll
            for (int ni = 0; ni < 4; ++ni) acc[mi][ni] = mfma16(af[mi], bf[ni], acc[mi][ni]);
    }
#pragma unroll
    for (int mi = 0; mi < 4; ++mi) {
#pragma unroll
        for (int ni = 0; ni < 4; ++ni) {
#pragma unroll
            for (int r = 0; r < 4; ++r) {
                const int row = m0 + wm + mi * 16 + (lane >> 4) * 4 + r;
                const int col = n0 + wn + ni * 16 + fr;
                if constexpr (OUT_F32)
                    ((float*)C)[(size_t)row * N + col] = acc[mi][ni][r];
                else
                    ((unsigned short*)C)[(size_t)row * N + col] = f2bf(acc[mi][ni][r]);
            }
        }
    }
}

// QKV projection: A = raw f32 inputs (inline cvt), B = pre-transposed bf16 weights.
__global__ __launch_bounds__(256) void gemm_qkv(
    const float* __restrict__ q, const float* __restrict__ k, const float* __restrict__ v,
    const unsigned short* __restrict__ wtq, const unsigned short* __restrict__ wtk,
    const unsigned short* __restrict__ wtv, unsigned short* __restrict__ Qp,
    unsigned short* __restrict__ Kp, unsigned short* __restrict__ Vp) {
    const float* A;
    const unsigned short* W;
    unsigned short* C;
    if (blockIdx.z == 0) { A = q; W = wtq; C = Qp; }
    else if (blockIdx.z == 1) { A = k; W = wtk; C = Kp; }
    else { A = v; W = wtv; C = Vp; }
    gemm_core<true, false>(A, W, C, blockIdx.x * TBM, blockIdx.y * TBN);
}

__global__ __launch_bounds__(256) void gemm_out(const unsigned short* __restrict__ Op,
                                                const unsigned short* __restrict__ wto,
                                                float* __restrict__ out) {
    gemm_core<false, true>(Op, wto, out, blockIdx.x * TBM, blockIdx.y * TBN);
}

// ---------------------------------------------------------------- windowed attention (MFMA)
// grid: (SEQ/64, NH, NB); 4 waves; wave qg owns queries [16qg,16qg+16).
// Window keys local l in [0,128): global j = t0-63+l. Query local i needs l in [i, i+63].
// Wave qg uses key 16-blocks kbg = qg..qg+4 (80 keys) -> 10 QK MFMAs, 12 PV MFMAs.
// kt [128][64] bf16 XOR-swz (granule ^= key&7); vT [64][128] bf16 XOR-swz (granule ^= d&15).
__global__ __launch_bounds__(256) void attn_win(const unsigned short* __restrict__ Qp,
                                                const unsigned short* __restrict__ Kp,
                                                const unsigned short* __restrict__ Vp,
                                                unsigned short* __restrict__ Op) {
    __shared__ __align__(16) unsigned short kt[128 * 64];   // 16 KB
    __shared__ __align__(16) unsigned short vT[64 * 128];   // 16 KB
    __shared__ __align__(16) unsigned short pw[4][16][104]; // 13 KB, per-wave P [q][ks]
    const int tile = blockIdx.x, h = blockIdx.y, b = blockIdx.z;
    const int t0 = tile * 64;
    const int tid = threadIdx.x;
    const int lane = tid & 63;
    const int qg = tid >> 6;        // wave id = query group
    const int c = lane & 15;
    const int g = lane >> 4;
    const int hcol = h * HD;
    const size_t base = (size_t)b * SEQ * DMODEL;

    // ---- stage K window (swizzled row-major) + V window (transposed, swizzled)
    {
        const int l = tid >> 1;             // 0..127
        const int dh = (tid & 1) * 32;      // dim half
        int j = t0 - (WSPAN - 1) + l;
        int jc = j < 0 ? 0 : (j > SEQ - 1 ? SEQ - 1 : j);  // clamped rows fully masked
        const unsigned short* kp = Kp + base + (size_t)jc * DMODEL + hcol + dh;
        const unsigned short* vp = Vp + base + (size_t)jc * DMODEL + hcol + dh;
        const int lg = (l & 7) << 4;
#pragma unroll
        for (int u = 0; u < 4; ++u) {
            const int dg = dh + u * 8;
            i32x4 kv = *(const i32x4*)(kp + u * 8);
            i32x4 vv = *(const i32x4*)(vp + u * 8);
            *(i32x4*)((char*)kt + l * 128 + ((dg * 2) ^ lg)) = kv;
#pragma unroll
            for (int e2 = 0; e2 < 4; ++e2) {
                unsigned int w2 = (unsigned int)vv[e2];
                const int d0 = dg + 2 * e2, d1 = d0 + 1;
                *(unsigned short*)((char*)vT + d0 * 256 + ((((l >> 3) ^ (d0 & 15)) << 4)) +
                                   (l & 7) * 2) = (unsigned short)(w2 & 0xffffu);
                *(unsigned short*)((char*)vT + d1 * 256 + ((((l >> 3) ^ (d1 & 15)) << 4)) +
                                   (l & 7) * 2) = (unsigned short)(w2 >> 16);
            }
        }
    }
    // zero P pad region ks in [80,96) (keeps PV K=96 exact)
    *(unsigned long long*)&pw[qg][lane >> 2][80 + (lane & 3) * 4] = 0ull;
    __syncthreads();

    // ---- QK^T: A = Q (direct global), B = K blocks from kt
    const unsigned short* qrow =
        Qp + base + (size_t)(t0 + 16 * qg + c) * DMODEL + hcol + 8 * g;
    const bf16x8 qa0 = *(const bf16x8*)qrow;
    const bf16x8 qa1 = *(const bf16x8*)(qrow + 32);
    f32x4 sacc[5];
#pragma unroll
    for (int kb = 0; kb < 5; ++kb) {
        sacc[kb] = (f32x4){0.f, 0.f, 0.f, 0.f};
        const int key = 16 * (qg + kb) + c;
        const int sw = (key & 7) << 4;
        bf16x8 kf0 = *(const bf16x8*)((const char*)kt + key * 128 + ((16 * g) ^ sw));
        bf16x8 kf1 = *(const bf16x8*)((const char*)kt + key * 128 + ((64 + 16 * g) ^ sw));
        sacc[kb] = mfma16(qa0, kf0, sacc[kb]);
        sacc[kb] = mfma16(qa1, kf1, sacc[kb]);
    }

    // ---- softmax in-register; C layout: col=c=key-in-block, row=4g+r=query-in-group
    const int L0 = 63 - t0;  // j>=0  <=>  l >= L0 (only binds in tile 0)
#pragma unroll
    for (int r = 0; r < 4; ++r) {
        const int iq = 4 * g + r;
        float sv[5];
        float m = -3e38f;
#pragma unroll
        for (int kb = 0; kb < 5; ++kb) {
            float x = sacc[kb][r] * 0.125f;  // 1/sqrt(64)
            const int dlk = 16 * kb + c - iq;              // l - i
            const int l = 16 * (qg + kb) + c;
            x = (dlk >= 0 && dlk <= 63 && l >= L0) ? x : -3e38f;
            sv[kb] = x;
            m = fmaxf(m, x);
        }
#pragma unroll
        for (int off = 1; off <= 8; off <<= 1) m = fmaxf(m, __shfl_xor(m, off));
        float s = 0.f;
#pragma unroll
        for (int kb = 0; kb < 5; ++kb) {
            float pp = __expf(sv[kb] - m);
            sv[kb] = pp;
            s += pp;
        }
#pragma unroll
        for (int off = 1; off <= 8; off <<= 1) s += __shfl_xor(s, off);
        const float rinv = 1.0f / s;
#pragma unroll
        for (int kb = 0; kb < 5; ++kb)
            pw[qg][iq][16 * kb + c] = f2bf(sv[kb] * rinv);
    }

    // ---- PV: A = P[16x32] from pw, B = V^T blocks from vT
    f32x4 oacc[4];
#pragma unroll
    for (int nb = 0; nb < 4; ++nb) oacc[nb] = (f32x4){0.f, 0.f, 0.f, 0.f};
#pragma unroll
    for (int ks = 0; ks < 3; ++ks) {
        const bf16x8 pa = *(const bf16x8*)&pw[qg][c][ks * 32 + 8 * g];
        const int lbase = 16 * qg + ks * 32 + 8 * g;
        // &15 clamp: lanes whose keys exceed the 128-key window read valid (wrong-but-
        // finite) vT data; their P is zero, so the product is exactly 0.
        const int gran = ((lbase >> 3) & 15) ^ c;
#pragma unroll
        for (int nb = 0; nb < 4; ++nb) {
            const bf16x8 vf =
                *(const bf16x8*)((const char*)vT + (16 * nb + c) * 256 + (gran << 4));
            oacc[nb] = mfma16(pa, vf, oacc[nb]);
        }
    }

    // ---- epilogue: C layout col=c (dim in block), row=4g+jr (query in group)
    unsigned short* orow = Op + base + (size_t)(t0 + 16 * qg + 4 * g) * DMODEL + hcol + c;
#pragma unroll
    for (int nb = 0; nb < 4; ++nb)
#pragma unroll
        for (int jr = 0; jr < 4; ++jr)
            orow[(size_t)jr * DMODEL + 16 * nb] = f2bf(oacc[nb][jr]);
}

// ---------------------------------------------------------------- launch
extern "C" void kernel_launch(void* const* d_in, const int* in_sizes, int n_in,
                              void* d_out, int out_size, void* d_ws, size_t ws_size,
                              hipStream_t stream) {
    (void)in_sizes; (void)n_in; (void)out_size; (void)ws_size;
    const float* q = (const float*)d_in[0];
    const float* k = (const float*)d_in[1];
    const float* v = (const float*)d_in[2];
    const float* Wq = (const float*)d_in[3];
    const float* Wk = (const float*)d_in[4];
    const float* Wv = (const float*)d_in[5];
    const float* Wout = (const float*)d_in[6];

    const size_t NBIG = (size_t)MROWS * DMODEL;  // 2,097,152
    const size_t NW = (size_t)DMODEL * DMODEL;   // 262,144
    unsigned short* p = (unsigned short*)d_ws;
    unsigned short* wtq = p; p += NW;   // transposed [N][K]
    unsigned short* wtk = p; p += NW;
    unsigned short* wtv = p; p += NW;
    unsigned short* wto = p; p += NW;
    unsigned short* Qp = p;  p += NBIG;
    unsigned short* Kp = p;  p += NBIG;
    unsigned short* Vp = p;  p += NBIG;
    unsigned short* Op = p;

    Wt4 w4;
    w4.src[0] = Wq;   w4.dst[0] = wtq;
    w4.src[1] = Wk;   w4.dst[1] = wtk;
    w4.src[2] = Wv;   w4.dst[2] = wtv;
    w4.src[3] = Wout; w4.dst[3] = wto;

    cvt_wT<<<dim3(8, 8, 4), 256, 0, stream>>>(w4);
    gemm_qkv<<<dim3(MROWS / TBM, DMODEL / TBN, 3), 256, 0, stream>>>(q, k, v, wtq, wtk, wtv,
                                                                     Qp, Kp, Vp);
    attn_win<<<dim3(SEQ / 64, NH, NB), 256, 0, stream>>>(Qp, Kp, Vp, Op);
    gemm_out<<<dim3(MROWS / TBM, DMODEL / TBN), 256, 0, stream>>>(Op, wto, (float*)d_out);
}

// Round 11
// 115.212 us; speedup vs baseline: 1.3325x; 1.0160x over previous
//
#include <hip/hip_runtime.h>

#define NB 2
#define SEQ 2048
#define NH 8
#define HD 64
#define DMODEL 512
#define WSPAN 64
#define MROWS (NB * SEQ) /* 4096 */

typedef __attribute__((ext_vector_type(4))) float f32x4;
typedef __attribute__((ext_vector_type(4))) int i32x4;
typedef __attribute__((ext_vector_type(8))) short bf16x8;

static __device__ __forceinline__ float bf2f(unsigned short u) {
    return __uint_as_float(((unsigned int)u) << 16);
}
static __device__ __forceinline__ unsigned short f2bf(float f) {
    unsigned int x = __float_as_uint(f);
    x += 0x7fffu + ((x >> 16) & 1u);   // RNE
    return (unsigned short)(x >> 16);
}
static __device__ __forceinline__ int pk2(float x, float y) {
    return (int)(((unsigned)f2bf(x)) | ((unsigned)f2bf(y) << 16));
}

// Builtin MFMA: compiler-visible -> hazard nops / waitcnts inserted by backend.
static __device__ __forceinline__ f32x4 mfma16(bf16x8 a, bf16x8 b, f32x4 c) {
    return __builtin_amdgcn_mfma_f32_16x16x32_bf16(a, b, c, 0, 0, 0);
}

// ---------------------------------------------------------------- weight cvt + transpose
// W [K=512][N=512] f32 -> WT [N][K] bf16, via 64x64 LDS tiles. grid (8,8,4).
struct Wt4 {
    const float* src[4];
    unsigned short* dst[4];
};

__global__ __launch_bounds__(256) void cvt_wT(Wt4 a) {
    __shared__ unsigned short t64[64][72];  // pad 8 -> write/read banks spread
    const int w = blockIdx.z;
    const float* src = a.src[w];
    unsigned short* dst = a.dst[w];
    const int k0 = blockIdx.x * 64, n0 = blockIdx.y * 64;
    const int t = threadIdx.x;
    const int r = t >> 2;             // 0..63
    const int cg = (t & 3) * 16;      // 0,16,32,48
    const float* sp = src + (size_t)(k0 + r) * DMODEL + n0 + cg;
#pragma unroll
    for (int j = 0; j < 16; j += 4) {
        float4 f = *(const float4*)(sp + j);
        t64[r][cg + j + 0] = f2bf(f.x);
        t64[r][cg + j + 1] = f2bf(f.y);
        t64[r][cg + j + 2] = f2bf(f.z);
        t64[r][cg + j + 3] = f2bf(f.w);
    }
    __syncthreads();
    unsigned short buf[16];
#pragma unroll
    for (int j = 0; j < 16; ++j) buf[j] = t64[cg + j][r];
    unsigned short* dp = dst + (size_t)(n0 + r) * DMODEL + k0 + cg;
    *(i32x4*)dp = *(const i32x4*)buf;
    *(i32x4*)(dp + 8) = *(const i32x4*)(buf + 8);
}

// ---------------------------------------------------------------- GEMM (A row-K f32|bf16, BT row-K bf16)
// TBM=64: gemm_qkv grid = 768 blocks = 3/CU exact; gemm_out = 256 = 1/CU exact
// (previous TBM=128 gave 1.5 / 0.5 blocks per CU -> makespan-doubling imbalance).
#define TBM 64
#define TBN 128
#define TBK 32
#define LPAD 40   // 80B rows: fragment b128 reads -> 2-way max (free)

template <bool A_F32, bool OUT_F32>
static __device__ __forceinline__ void gemm_core(const void* __restrict__ Av,
                                                 const unsigned short* __restrict__ BT,
                                                 void* __restrict__ C, int m0, int n0) {
    constexpr int N = DMODEL, K = DMODEL;
    constexpr int NSTEP = K / TBK;  // 16
    __shared__ __align__(16) unsigned short a_lds[TBM][LPAD];
    __shared__ __align__(16) unsigned short b_lds[TBN][LPAD];
    const int t = threadIdx.x;
    const int lane = t & 63;
    const int wv = t >> 6;
    // staging coords: A 64x32 -> 8 elems/thread; B 128x32 -> 16 elems/thread
    const int s_ar = t >> 2;          // 0..63
    const int s_ak = (t & 3) * 8;     // 0,8,16,24
    const int s_br = t >> 1;          // 0..127
    const int s_bk = (t & 1) * 16;    // 0 or 16
    // fragment coords (verified layout: row/col = lane&15, k = (lane>>4)*8)
    const int fr = lane & 15;
    const int fk = (lane >> 4) * 8;
    const int wm = (wv & 1) * 32;
    const int wn = (wv >> 1) * 64;

    f32x4 acc[2][4];
#pragma unroll
    for (int i = 0; i < 2; ++i)
#pragma unroll
        for (int j = 0; j < 4; ++j) acc[i][j] = (f32x4){0.f, 0.f, 0.f, 0.f};

    i32x4 a0, b0, b1;
    auto load_ab = [&](int k0) {
        if constexpr (A_F32) {
            const float* ap = (const float*)Av + (size_t)(m0 + s_ar) * K + k0 + s_ak;
            float4 f0 = *(const float4*)ap;
            float4 f1 = *(const float4*)(ap + 4);
            a0 = (i32x4){pk2(f0.x, f0.y), pk2(f0.z, f0.w), pk2(f1.x, f1.y), pk2(f1.z, f1.w)};
        } else {
            const unsigned short* ap =
                (const unsigned short*)Av + (size_t)(m0 + s_ar) * K + k0 + s_ak;
            a0 = *(const i32x4*)ap;
        }
        const unsigned short* bp = BT + (size_t)(n0 + s_br) * K + k0 + s_bk;
        b0 = *(const i32x4*)bp;
        b1 = *(const i32x4*)(bp + 8);
    };

    load_ab(0);
    for (int ks = 0; ks < NSTEP; ++ks) {
        __syncthreads();   // previous step's fragment reads complete
        *(i32x4*)&a_lds[s_ar][s_ak] = a0;
        *(i32x4*)&b_lds[s_br][s_bk] = b0;
        *(i32x4*)&b_lds[s_br][s_bk + 8] = b1;
        __syncthreads();   // LDS visible
        // issue next-tile global loads; latency hides under the MFMA cluster
        const int kn = (ks + 1 < NSTEP) ? (ks + 1) * TBK : ks * TBK;
        load_ab(kn);
        bf16x8 af[2], bf[4];
#pragma unroll
        for (int i = 0; i < 2; ++i) af[i] = *(const bf16x8*)&a_lds[wm + i * 16 + fr][fk];
#pragma unroll
        for (int i = 0; i < 4; ++i) bf[i] = *(const bf16x8*)&b_lds[wn + i * 16 + fr][fk];
#pragma unroll
        for (int mi = 0; mi < 2; ++mi)
#pragma unroll
            for (int ni = 0; ni < 4; ++ni) acc[mi][ni] = mfma16(af[mi], bf[ni], acc[mi][ni]);
    }
#pragma unroll
    for (int mi = 0; mi < 2; ++mi) {
#pragma unroll
        for (int ni = 0; ni < 4; ++ni) {
#pragma unroll
            for (int r = 0; r < 4; ++r) {
                const int row = m0 + wm + mi * 16 + (lane >> 4) * 4 + r;
                const int col = n0 + wn + ni * 16 + fr;
                if constexpr (OUT_F32)
                    ((float*)C)[(size_t)row * N + col] = acc[mi][ni][r];
                else
                    ((unsigned short*)C)[(size_t)row * N + col] = f2bf(acc[mi][ni][r]);
            }
        }
    }
}

// QKV projection: A = raw f32 inputs (inline cvt), B = pre-transposed bf16 weights.
__global__ __launch_bounds__(256) void gemm_qkv(
    const float* __restrict__ q, const float* __restrict__ k, const float* __restrict__ v,
    const unsigned short* __restrict__ wtq, const unsigned short* __restrict__ wtk,
    const unsigned short* __restrict__ wtv, unsigned short* __restrict__ Qp,
    unsigned short* __restrict__ Kp, unsigned short* __restrict__ Vp) {
    const float* A;
    const unsigned short* W;
    unsigned short* C;
    if (blockIdx.z == 0) { A = q; W = wtq; C = Qp; }
    else if (blockIdx.z == 1) { A = k; W = wtk; C = Kp; }
    else { A = v; W = wtv; C = Vp; }
    gemm_core<true, false>(A, W, C, blockIdx.x * TBM, blockIdx.y * TBN);
}

__global__ __launch_bounds__(256) void gemm_out(const unsigned short* __restrict__ Op,
                                                const unsigned short* __restrict__ wto,
                                                float* __restrict__ out) {
    gemm_core<false, true>(Op, wto, out, blockIdx.x * TBM, blockIdx.y * TBN);
}

// ---------------------------------------------------------------- windowed attention (MFMA)
// grid: (SEQ/64, NH, NB); 4 waves; wave qg owns queries [16qg,16qg+16).
// Window keys local l in [0,128): global j = t0-63+l. Query local i needs l in [i, i+63].
// Wave qg uses key 16-blocks kbg = qg..qg+4 (80 keys) -> 10 QK MFMAs, 12 PV MFMAs.
// kt [128][64] bf16 XOR-swz (granule ^= key&7); vT [64][128] bf16 XOR-swz (granule ^= d&15).
__global__ __launch_bounds__(256) void attn_win(const unsigned short* __restrict__ Qp,
                                                const unsigned short* __restrict__ Kp,
                                                const unsigned short* __restrict__ Vp,
                                                unsigned short* __restrict__ Op) {
    __shared__ __align__(16) unsigned short kt[128 * 64];   // 16 KB
    __shared__ __align__(16) unsigned short vT[64 * 128];   // 16 KB
    __shared__ __align__(16) unsigned short pw[4][16][104]; // 13 KB, per-wave P [q][ks]
    const int tile = blockIdx.x, h = blockIdx.y, b = blockIdx.z;
    const int t0 = tile * 64;
    const int tid = threadIdx.x;
    const int lane = tid & 63;
    const int qg = tid >> 6;        // wave id = query group
    const int c = lane & 15;
    const int g = lane >> 4;
    const int hcol = h * HD;
    const size_t base = (size_t)b * SEQ * DMODEL;

    // ---- Q fragment loads issued FIRST: HBM latency overlaps the staging phase
    const unsigned short* qrow =
        Qp + base + (size_t)(t0 + 16 * qg + c) * DMODEL + hcol + 8 * g;
    const bf16x8 qa0 = *(const bf16x8*)qrow;
    const bf16x8 qa1 = *(const bf16x8*)(qrow + 32);

    // ---- stage K window (swizzled row-major) + V window (transposed, swizzled)
    {
        const int l = tid >> 1;             // 0..127
        const int dh = (tid & 1) * 32;      // dim half
        int j = t0 - (WSPAN - 1) + l;
        int jc = j < 0 ? 0 : (j > SEQ - 1 ? SEQ - 1 : j);  // clamped rows fully masked
        const unsigned short* kp = Kp + base + (size_t)jc * DMODEL + hcol + dh;
        const unsigned short* vp = Vp + base + (size_t)jc * DMODEL + hcol + dh;
        const int lg = (l & 7) << 4;
#pragma unroll
        for (int u = 0; u < 4; ++u) {
            const int dg = dh + u * 8;
            i32x4 kv = *(const i32x4*)(kp + u * 8);
            i32x4 vv = *(const i32x4*)(vp + u * 8);
            *(i32x4*)((char*)kt + l * 128 + ((dg * 2) ^ lg)) = kv;
#pragma unroll
            for (int e2 = 0; e2 < 4; ++e2) {
                unsigned int w2 = (unsigned int)vv[e2];
                const int d0 = dg + 2 * e2, d1 = d0 + 1;
                *(unsigned short*)((char*)vT + d0 * 256 + ((((l >> 3) ^ (d0 & 15)) << 4)) +
                                   (l & 7) * 2) = (unsigned short)(w2 & 0xffffu);
                *(unsigned short*)((char*)vT + d1 * 256 + ((((l >> 3) ^ (d1 & 15)) << 4)) +
                                   (l & 7) * 2) = (unsigned short)(w2 >> 16);
            }
        }
    }
    // zero P pad region ks in [80,96) (keeps PV K=96 exact)
    *(unsigned long long*)&pw[qg][lane >> 2][80 + (lane & 3) * 4] = 0ull;
    __syncthreads();

    // ---- QK^T: A = Q (in registers), B = K blocks from kt
    f32x4 sacc[5];
#pragma unroll
    for (int kb = 0; kb < 5; ++kb) {
        sacc[kb] = (f32x4){0.f, 0.f, 0.f, 0.f};
        const int key = 16 * (qg + kb) + c;
        const int sw = (key & 7) << 4;
        bf16x8 kf0 = *(const bf16x8*)((const char*)kt + key * 128 + ((16 * g) ^ sw));
        bf16x8 kf1 = *(const bf16x8*)((const char*)kt + key * 128 + ((64 + 16 * g) ^ sw));
        sacc[kb] = mfma16(qa0, kf0, sacc[kb]);
        sacc[kb] = mfma16(qa1, kf1, sacc[kb]);
    }

    // ---- softmax in-register; C layout: col=c=key-in-block, row=4g+r=query-in-group
    const int L0 = 63 - t0;  // j>=0  <=>  l >= L0 (only binds in tile 0)
#pragma unroll
    for (int r = 0; r < 4; ++r) {
        const int iq = 4 * g + r;
        float sv[5];
        float m = -3e38f;
#pragma unroll
        for (int kb = 0; kb < 5; ++kb) {
            float x = sacc[kb][r] * 0.125f;  // 1/sqrt(64)
            const int dlk = 16 * kb + c - iq;              // l - i
            const int l = 16 * (qg + kb) + c;
            x = (dlk >= 0 && dlk <= 63 && l >= L0) ? x : -3e38f;
            sv[kb] = x;
            m = fmaxf(m, x);
        }
#pragma unroll
        for (int off = 1; off <= 8; off <<= 1) m = fmaxf(m, __shfl_xor(m, off));
        float s = 0.f;
#pragma unroll
        for (int kb = 0; kb < 5; ++kb) {
            float pp = __expf(sv[kb] - m);
            sv[kb] = pp;
            s += pp;
        }
#pragma unroll
        for (int off = 1; off <= 8; off <<= 1) s += __shfl_xor(s, off);
        const float rinv = 1.0f / s;
#pragma unroll
        for (int kb = 0; kb < 5; ++kb)
            pw[qg][iq][16 * kb + c] = f2bf(sv[kb] * rinv);
    }

    // ---- PV: A = P[16x32] from pw, B = V^T blocks from vT
    f32x4 oacc[4];
#pragma unroll
    for (int nb = 0; nb < 4; ++nb) oacc[nb] = (f32x4){0.f, 0.f, 0.f, 0.f};
#pragma unroll
    for (int ks = 0; ks < 3; ++ks) {
        const bf16x8 pa = *(const bf16x8*)&pw[qg][c][ks * 32 + 8 * g];
        const int lbase = 16 * qg + ks * 32 + 8 * g;
        // &15 clamp: lanes whose keys exceed the 128-key window read valid (wrong-but-
        // finite) vT data; their P is zero, so the product is exactly 0.
        const int gran = ((lbase >> 3) & 15) ^ c;
#pragma unroll
        for (int nb = 0; nb < 4; ++nb) {
            const bf16x8 vf =
                *(const bf16x8*)((const char*)vT + (16 * nb + c) * 256 + (gran << 4));
            oacc[nb] = mfma16(pa, vf, oacc[nb]);
        }
    }

    // ---- epilogue: C layout col=c (dim in block), row=4g+jr (query in group)
    unsigned short* orow = Op + base + (size_t)(t0 + 16 * qg + 4 * g) * DMODEL + hcol + c;
#pragma unroll
    for (int nb = 0; nb < 4; ++nb)
#pragma unroll
        for (int jr = 0; jr < 4; ++jr)
            orow[(size_t)jr * DMODEL + 16 * nb] = f2bf(oacc[nb][jr]);
}

// ---------------------------------------------------------------- launch
extern "C" void kernel_launch(void* const* d_in, const int* in_sizes, int n_in,
                              void* d_out, int out_size, void* d_ws, size_t ws_size,
                              hipStream_t stream) {
    (void)in_sizes; (void)n_in; (void)out_size; (void)ws_size;
    const float* q = (const float*)d_in[0];
    const float* k = (const float*)d_in[1];
    const float* v = (const float*)d_in[2];
    const float* Wq = (const float*)d_in[3];
    const float* Wk = (const float*)d_in[4];
    const float* Wv = (const float*)d_in[5];
    const float* Wout = (const float*)d_in[6];

    const size_t NBIG = (size_t)MROWS * DMODEL;  // 2,097,152
    const size_t NW = (size_t)DMODEL * DMODEL;   // 262,144
    unsigned short* p = (unsigned short*)d_ws;
    unsigned short* wtq = p; p += NW;   // transposed [N][K]
    unsigned short* wtk = p; p += NW;
    unsigned short* wtv = p; p += NW;
    unsigned short* wto = p; p += NW;
    unsigned short* Qp = p;  p += NBIG;
    unsigned short* Kp = p;  p += NBIG;
    unsigned short* Vp = p;  p += NBIG;
    unsigned short* Op = p;

    Wt4 w4;
    w4.src[0] = Wq;   w4.dst[0] = wtq;
    w4.src[1] = Wk;   w4.dst[1] = wtk;
    w4.src[2] = Wv;   w4.dst[2] = wtv;
    w4.src[3] = Wout; w4.dst[3] = wto;

    cvt_wT<<<dim3(8, 8, 4), 256, 0, stream>>>(w4);
    gemm_qkv<<<dim3(MROWS / TBM, DMODEL / TBN, 3), 256, 0, stream>>>(q, k, v, wtq, wtk, wtv,
                                                                     Qp, Kp, Vp);
    attn_win<<<dim3(SEQ / 64, NH, NB), 256, 0, stream>>>(Qp, Kp, Vp, Op);
    gemm_out<<<dim3(MROWS / TBM, DMODEL / TBN), 256, 0, stream>>>(Op, wto, (float*)d_out);
}

// Round 12
// 114.793 us; speedup vs baseline: 1.3374x; 1.0037x over previous
//
#include <hip/hip_runtime.h>

#define NB 2
#define SEQ 2048
#define NH 8
#define HD 64
#define DMODEL 512
#define WSPAN 64
#define MROWS (NB * SEQ) /* 4096 */

typedef __attribute__((ext_vector_type(4))) float f32x4;
typedef __attribute__((ext_vector_type(4))) int i32x4;
typedef __attribute__((ext_vector_type(8))) short bf16x8;

static __device__ __forceinline__ float bf2f(unsigned short u) {
    return __uint_as_float(((unsigned int)u) << 16);
}
static __device__ __forceinline__ unsigned short f2bf(float f) {
    unsigned int x = __float_as_uint(f);
    x += 0x7fffu + ((x >> 16) & 1u);   // RNE
    return (unsigned short)(x >> 16);
}
static __device__ __forceinline__ int pk2(float x, float y) {
    return (int)(((unsigned)f2bf(x)) | ((unsigned)f2bf(y) << 16));
}

// Builtin MFMA: compiler-visible -> hazard nops / waitcnts inserted by backend.
static __device__ __forceinline__ f32x4 mfma16(bf16x8 a, bf16x8 b, f32x4 c) {
    return __builtin_amdgcn_mfma_f32_16x16x32_bf16(a, b, c, 0, 0, 0);
}

// ---------------------------------------------------------------- weight cvt + transpose
// W [K=512][N=512] f32 -> WT [N][K] bf16, via 64x64 LDS tiles. grid (8,8,4).
struct Wt4 {
    const float* src[4];
    unsigned short* dst[4];
};

__global__ __launch_bounds__(256) void cvt_wT(Wt4 a) {
    __shared__ unsigned short t64[64][72];  // pad 8 -> write/read banks spread
    const int w = blockIdx.z;
    const float* src = a.src[w];
    unsigned short* dst = a.dst[w];
    const int k0 = blockIdx.x * 64, n0 = blockIdx.y * 64;
    const int t = threadIdx.x;
    const int r = t >> 2;             // 0..63
    const int cg = (t & 3) * 16;      // 0,16,32,48
    const float* sp = src + (size_t)(k0 + r) * DMODEL + n0 + cg;
#pragma unroll
    for (int j = 0; j < 16; j += 4) {
        float4 f = *(const float4*)(sp + j);
        t64[r][cg + j + 0] = f2bf(f.x);
        t64[r][cg + j + 1] = f2bf(f.y);
        t64[r][cg + j + 2] = f2bf(f.z);
        t64[r][cg + j + 3] = f2bf(f.w);
    }
    __syncthreads();
    unsigned short buf[16];
#pragma unroll
    for (int j = 0; j < 16; ++j) buf[j] = t64[cg + j][r];
    unsigned short* dp = dst + (size_t)(n0 + r) * DMODEL + k0 + cg;
    *(i32x4*)dp = *(const i32x4*)buf;
    *(i32x4*)(dp + 8) = *(const i32x4*)(buf + 8);
}

// ---------------------------------------------------------------- GEMM (A row-K f32|bf16, BT row-K bf16)
// TBM=64: gemm_qkv grid = 768 blocks = 3/CU exact; gemm_out = 256 = 1/CU exact.
#define TBM 64
#define TBN 128
#define TBK 32
#define LPAD 40   // 80B rows: fragment b128 reads -> 2-way max (free)

template <bool A_F32, bool OUT_F32>
static __device__ __forceinline__ void gemm_core(const void* __restrict__ Av,
                                                 const unsigned short* __restrict__ BT,
                                                 void* __restrict__ C, int m0, int n0) {
    constexpr int N = DMODEL, K = DMODEL;
    constexpr int NSTEP = K / TBK;  // 16
    __shared__ __align__(16) unsigned short a_lds[TBM][LPAD];
    __shared__ __align__(16) unsigned short b_lds[TBN][LPAD];
    const int t = threadIdx.x;
    const int lane = t & 63;
    const int wv = t >> 6;
    // staging coords: A 64x32 -> 8 elems/thread; B 128x32 -> 16 elems/thread
    const int s_ar = t >> 2;          // 0..63
    const int s_ak = (t & 3) * 8;     // 0,8,16,24
    const int s_br = t >> 1;          // 0..127
    const int s_bk = (t & 1) * 16;    // 0 or 16
    // fragment coords (verified layout: row/col = lane&15, k = (lane>>4)*8)
    const int fr = lane & 15;
    const int fk = (lane >> 4) * 8;
    const int wm = (wv & 1) * 32;
    const int wn = (wv >> 1) * 64;

    f32x4 acc[2][4];
#pragma unroll
    for (int i = 0; i < 2; ++i)
#pragma unroll
        for (int j = 0; j < 4; ++j) acc[i][j] = (f32x4){0.f, 0.f, 0.f, 0.f};

    i32x4 a0, b0, b1;
    auto load_ab = [&](int k0) {
        if constexpr (A_F32) {
            const float* ap = (const float*)Av + (size_t)(m0 + s_ar) * K + k0 + s_ak;
            float4 f0 = *(const float4*)ap;
            float4 f1 = *(const float4*)(ap + 4);
            a0 = (i32x4){pk2(f0.x, f0.y), pk2(f0.z, f0.w), pk2(f1.x, f1.y), pk2(f1.z, f1.w)};
        } else {
            const unsigned short* ap =
                (const unsigned short*)Av + (size_t)(m0 + s_ar) * K + k0 + s_ak;
            a0 = *(const i32x4*)ap;
        }
        const unsigned short* bp = BT + (size_t)(n0 + s_br) * K + k0 + s_bk;
        b0 = *(const i32x4*)bp;
        b1 = *(const i32x4*)(bp + 8);
    };

    load_ab(0);
    for (int ks = 0; ks < NSTEP; ++ks) {
        __syncthreads();   // previous step's fragment reads complete
        *(i32x4*)&a_lds[s_ar][s_ak] = a0;
        *(i32x4*)&b_lds[s_br][s_bk] = b0;
        *(i32x4*)&b_lds[s_br][s_bk + 8] = b1;
        __syncthreads();   // LDS visible
        // issue next-tile global loads; latency hides under the MFMA cluster
        const int kn = (ks + 1 < NSTEP) ? (ks + 1) * TBK : ks * TBK;
        load_ab(kn);
        bf16x8 af[2], bf[4];
#pragma unroll
        for (int i = 0; i < 2; ++i) af[i] = *(const bf16x8*)&a_lds[wm + i * 16 + fr][fk];
#pragma unroll
        for (int i = 0; i < 4; ++i) bf[i] = *(const bf16x8*)&b_lds[wn + i * 16 + fr][fk];
#pragma unroll
        for (int mi = 0; mi < 2; ++mi)
#pragma unroll
            for (int ni = 0; ni < 4; ++ni) acc[mi][ni] = mfma16(af[mi], bf[ni], acc[mi][ni]);
    }
#pragma unroll
    for (int mi = 0; mi < 2; ++mi) {
#pragma unroll
        for (int ni = 0; ni < 4; ++ni) {
#pragma unroll
            for (int r = 0; r < 4; ++r) {
                const int row = m0 + wm + mi * 16 + (lane >> 4) * 4 + r;
                const int col = n0 + wn + ni * 16 + fr;
                if constexpr (OUT_F32)
                    ((float*)C)[(size_t)row * N + col] = acc[mi][ni][r];
                else
                    ((unsigned short*)C)[(size_t)row * N + col] = f2bf(acc[mi][ni][r]);
            }
        }
    }
}

// QKV projection: A = raw f32 inputs (inline cvt), B = pre-transposed bf16 weights.
__global__ __launch_bounds__(256) void gemm_qkv(
    const float* __restrict__ q, const float* __restrict__ k, const float* __restrict__ v,
    const unsigned short* __restrict__ wtq, const unsigned short* __restrict__ wtk,
    const unsigned short* __restrict__ wtv, unsigned short* __restrict__ Qp,
    unsigned short* __restrict__ Kp, unsigned short* __restrict__ Vp) {
    const float* A;
    const unsigned short* W;
    unsigned short* C;
    if (blockIdx.z == 0) { A = q; W = wtq; C = Qp; }
    else if (blockIdx.z == 1) { A = k; W = wtk; C = Kp; }
    else { A = v; W = wtv; C = Vp; }
    gemm_core<true, false>(A, W, C, blockIdx.x * TBM, blockIdx.y * TBN);
}

__global__ __launch_bounds__(256) void gemm_out(const unsigned short* __restrict__ Op,
                                                const unsigned short* __restrict__ wto,
                                                float* __restrict__ out) {
    gemm_core<false, true>(Op, wto, out, blockIdx.x * TBM, blockIdx.y * TBN);
}

// ---------------------------------------------------------------- windowed attention (MFMA)
// grid: (SEQ/64, NH, NB); 4 waves; wave qg owns queries [16qg,16qg+16).
// K fragments read DIRECTLY from global (16KB window is L1-resident, fragment-shaped:
// lanes g=0..3 of a key form one 64B line). Only V is LDS-staged (transposed + swizzled).
__global__ __launch_bounds__(256) void attn_win(const unsigned short* __restrict__ Qp,
                                                const unsigned short* __restrict__ Kp,
                                                const unsigned short* __restrict__ Vp,
                                                unsigned short* __restrict__ Op) {
    __shared__ __align__(16) unsigned short vT[64 * 128];   // 16 KB
    __shared__ __align__(16) unsigned short pw[4][16][104]; // 13 KB, per-wave P [q][ks]
    const int tile = blockIdx.x, h = blockIdx.y, b = blockIdx.z;
    const int t0 = tile * 64;
    const int tid = threadIdx.x;
    const int lane = tid & 63;
    const int qg = tid >> 6;        // wave id = query group
    const int c = lane & 15;
    const int g = lane >> 4;
    const int hcol = h * HD;
    const size_t base = (size_t)b * SEQ * DMODEL;

    // ---- Q fragment loads issued FIRST: HBM latency overlaps the staging phase
    const unsigned short* qrow =
        Qp + base + (size_t)(t0 + 16 * qg + c) * DMODEL + hcol + 8 * g;
    const bf16x8 qa0 = *(const bf16x8*)qrow;
    const bf16x8 qa1 = *(const bf16x8*)(qrow + 32);

    // ---- stage V window only (transposed, swizzled)
    {
        const int l = tid >> 1;             // 0..127
        const int dh = (tid & 1) * 32;      // dim half
        int j = t0 - (WSPAN - 1) + l;
        int jc = j < 0 ? 0 : (j > SEQ - 1 ? SEQ - 1 : j);  // clamped rows fully masked
        const unsigned short* vp = Vp + base + (size_t)jc * DMODEL + hcol + dh;
#pragma unroll
        for (int u = 0; u < 4; ++u) {
            const int dg = dh + u * 8;
            i32x4 vv = *(const i32x4*)(vp + u * 8);
#pragma unroll
            for (int e2 = 0; e2 < 4; ++e2) {
                unsigned int w2 = (unsigned int)vv[e2];
                const int d0 = dg + 2 * e2, d1 = d0 + 1;
                *(unsigned short*)((char*)vT + d0 * 256 + ((((l >> 3) ^ (d0 & 15)) << 4)) +
                                   (l & 7) * 2) = (unsigned short)(w2 & 0xffffu);
                *(unsigned short*)((char*)vT + d1 * 256 + ((((l >> 3) ^ (d1 & 15)) << 4)) +
                                   (l & 7) * 2) = (unsigned short)(w2 >> 16);
            }
        }
    }
    // zero P pad region ks in [80,96) (keeps PV K=96 exact)
    *(unsigned long long*)&pw[qg][lane >> 2][80 + (lane & 3) * 4] = 0ull;
    __syncthreads();

    // ---- QK^T: A = Q (registers), B = K fragments direct from global (L1-resident)
    f32x4 sacc[5];
#pragma unroll
    for (int kb = 0; kb < 5; ++kb) {
        sacc[kb] = (f32x4){0.f, 0.f, 0.f, 0.f};
        const int l = 16 * (qg + kb) + c;        // local key 0..127
        int j = t0 - (WSPAN - 1) + l;
        int jc = j < 0 ? 0 : (j > SEQ - 1 ? SEQ - 1 : j);  // clamped cols masked below
        const unsigned short* krow = Kp + base + (size_t)jc * DMODEL + hcol + 8 * g;
        bf16x8 kf0 = *(const bf16x8*)krow;
        bf16x8 kf1 = *(const bf16x8*)(krow + 32);
        sacc[kb] = mfma16(qa0, kf0, sacc[kb]);
        sacc[kb] = mfma16(qa1, kf1, sacc[kb]);
    }

    // ---- softmax in-register; C layout: col=c=key-in-block, row=4g+r=query-in-group
    const int L0 = 63 - t0;  // j>=0  <=>  l >= L0 (only binds in tile 0)
#pragma unroll
    for (int r = 0; r < 4; ++r) {
        const int iq = 4 * g + r;
        float sv[5];
        float m = -3e38f;
#pragma unroll
        for (int kb = 0; kb < 5; ++kb) {
            float x = sacc[kb][r] * 0.125f;  // 1/sqrt(64)
            const int dlk = 16 * kb + c - iq;              // l - i
            const int l = 16 * (qg + kb) + c;
            x = (dlk >= 0 && dlk <= 63 && l >= L0) ? x : -3e38f;
            sv[kb] = x;
            m = fmaxf(m, x);
        }
#pragma unroll
        for (int off = 1; off <= 8; off <<= 1) m = fmaxf(m, __shfl_xor(m, off));
        float s = 0.f;
#pragma unroll
        for (int kb = 0; kb < 5; ++kb) {
            float pp = __expf(sv[kb] - m);
            sv[kb] = pp;
            s += pp;
        }
#pragma unroll
        for (int off = 1; off <= 8; off <<= 1) s += __shfl_xor(s, off);
        const float rinv = 1.0f / s;
#pragma unroll
        for (int kb = 0; kb < 5; ++kb)
            pw[qg][iq][16 * kb + c] = f2bf(sv[kb] * rinv);
    }

    // ---- PV: A = P[16x32] from pw, B = V^T blocks from vT
    f32x4 oacc[4];
#pragma unroll
    for (int nb = 0; nb < 4; ++nb) oacc[nb] = (f32x4){0.f, 0.f, 0.f, 0.f};
#pragma unroll
    for (int ks = 0; ks < 3; ++ks) {
        const bf16x8 pa = *(const bf16x8*)&pw[qg][c][ks * 32 + 8 * g];
        const int lbase = 16 * qg + ks * 32 + 8 * g;
        // &15 clamp: lanes whose keys exceed the 128-key window read valid (wrong-but-
        // finite) vT data; their P is zero, so the product is exactly 0.
        const int gran = ((lbase >> 3) & 15) ^ c;
#pragma unroll
        for (int nb = 0; nb < 4; ++nb) {
            const bf16x8 vf =
                *(const bf16x8*)((const char*)vT + (16 * nb + c) * 256 + (gran << 4));
            oacc[nb] = mfma16(pa, vf, oacc[nb]);
        }
    }

    // ---- epilogue: C layout col=c (dim in block), row=4g+jr (query in group)
    unsigned short* orow = Op + base + (size_t)(t0 + 16 * qg + 4 * g) * DMODEL + hcol + c;
#pragma unroll
    for (int nb = 0; nb < 4; ++nb)
#pragma unroll
        for (int jr = 0; jr < 4; ++jr)
            orow[(size_t)jr * DMODEL + 16 * nb] = f2bf(oacc[nb][jr]);
}

// ---------------------------------------------------------------- launch
extern "C" void kernel_launch(void* const* d_in, const int* in_sizes, int n_in,
                              void* d_out, int out_size, void* d_ws, size_t ws_size,
                              hipStream_t stream) {
    (void)in_sizes; (void)n_in; (void)out_size; (void)ws_size;
    const float* q = (const float*)d_in[0];
    const float* k = (const float*)d_in[1];
    const float* v = (const float*)d_in[2];
    const float* Wq = (const float*)d_in[3];
    const float* Wk = (const float*)d_in[4];
    const float* Wv = (const float*)d_in[5];
    const float* Wout = (const float*)d_in[6];

    const size_t NBIG = (size_t)MROWS * DMODEL;  // 2,097,152
    const size_t NW = (size_t)DMODEL * DMODEL;   // 262,144
    unsigned short* p = (unsigned short*)d_ws;
    unsigned short* wtq = p; p += NW;   // transposed [N][K]
    unsigned short* wtk = p; p += NW;
    unsigned short* wtv = p; p += NW;
    unsigned short* wto = p; p += NW;
    unsigned short* Qp = p;  p += NBIG;
    unsigned short* Kp = p;  p += NBIG;
    unsigned short* Vp = p;  p += NBIG;
    unsigned short* Op = p;

    Wt4 w4;
    w4.src[0] = Wq;   w4.dst[0] = wtq;
    w4.src[1] = Wk;   w4.dst[1] = wtk;
    w4.src[2] = Wv;   w4.dst[2] = wtv;
    w4.src[3] = Wout; w4.dst[3] = wto;

    cvt_wT<<<dim3(8, 8, 4), 256, 0, stream>>>(w4);
    gemm_qkv<<<dim3(MROWS / TBM, DMODEL / TBN, 3), 256, 0, stream>>>(q, k, v, wtq, wtk, wtv,
                                                                     Qp, Kp, Vp);
    attn_win<<<dim3(SEQ / 64, NH, NB), 256, 0, stream>>>(Qp, Kp, Vp, Op);
    gemm_out<<<dim3(MROWS / TBM, DMODEL / TBN), 256, 0, stream>>>(Op, wto, (float*)d_out);
}